// Round 14
// baseline (906.623 us; speedup 1.0000x reference)
//
#include <hip/hip_runtime.h>
#include <hip/hip_bf16.h>
#include <hip/hip_cooperative_groups.h>

namespace cg = cooperative_groups;

#define B 8
#define N 8192
#define E 65536
#define FIN 64
#define H 128
#define OUTD 256
#define NLAYER 3
#define EPS 1e-5f
#define NCHUNK 128               // pool chunks per batch (one per 64-row layer unit)
#define NNODE (B * N)            // 65536 rows
#define KSTEPS 8                 // 2 groups x 4 k-steps of K=32 (xh*sWhi, nh*nWhi)
#define BPL (KSTEPS * 8 * 512)   // Bp ushort elems per layer
#define INSTEPS 6                // inproj: 3 groups x 2 k-steps (fh*Whi, fl*Whi, fh*Wlo)
#define ELLW 48                  // max incoming edges/node (Poisson(8): P(>48) ~ 1e-25)

#define AS1 __attribute__((address_space(1)))
#define AS3 __attribute__((address_space(3)))

typedef float f32x4 __attribute__((ext_vector_type(4)));
typedef __bf16 bf16x8 __attribute__((ext_vector_type(8)));

__device__ __forceinline__ float b2f(unsigned short u) {
    union { float f; unsigned int i; } c; c.i = ((unsigned int)u) << 16; return c.f;
}
__device__ __forceinline__ unsigned short f2b(float f) {
    __hip_bfloat16 h = __float2bfloat16(f);          // RTNE
    return *reinterpret_cast<unsigned short*>(&h);
}

struct MegaArgs {
    const float *feats; const int *ei; const float *nmask; const float *emask;
    const float *inW, *inb, *selfW, *selfb, *neighW, *neighb, *lng, *lnb;
    const float *W1, *b1, *W2, *b2;
    float *out;
    unsigned short *xh, *nh, *Bp, *Bpi;
    float *part, *part2;
    int *ecnt; unsigned int *ell;
};

// ==================== single cooperative mega-kernel ====================
__global__ __launch_bounds__(256, 4) void k_mega(MegaArgs A) {
    cg::grid_group grid = cg::this_grid();
    __shared__ __align__(16) unsigned short bbuf[2][16 * 512];   // 32 KB
    __shared__ float lsum[2][64], lsq[2][64];
    __shared__ float psum_s[2][H], pmax_s[2][H];

    const int bid = blockIdx.x, tid = threadIdx.x, GD = gridDim.x;
    const int wv = tid >> 6, lane = tid & 63;
    const int quad = lane >> 4, col = lane & 15;

    // ---------- P0: zero ecnt + weight pre-pack ----------
    for (int i = bid * 256 + tid; i < NNODE; i += GD * 256) A.ecnt[i] = 0;
    for (int u4 = bid; u4 < 60; u4 += GD) {
        const int idx = u4 * 4 + wv;            // 240 prep units, 64 threads each
        if (idx < NLAYER * KSTEPS * 8) {
            const int t = idx & 7;
            const int s = (idx >> 3) % KSTEPS;
            const int l = idx / (KSTEPS * 8);
            const float* W = (((s >> 2) == 0) ? A.selfW : A.neighW) + (size_t)l * H * H;
            const int n = t * 16 + col;
            unsigned short* dst = A.Bp + ((size_t)(l * KSTEPS + s) * 8 + t) * 512 + lane * 8;
            #pragma unroll
            for (int j = 0; j < 8; ++j)
                dst[j] = f2b(W[((s & 3) * 32 + quad * 8 + j) * H + n]);
        } else {
            const int idx2 = idx - NLAYER * KSTEPS * 8;
            const int t = idx2 & 7;
            const int s = idx2 >> 3;            // 0..5
            const bool lo = ((s >> 1) == 2);
            const int n = t * 16 + col;
            unsigned short* dst = A.Bpi + ((size_t)(s * 8 + t)) * 512 + lane * 8;
            #pragma unroll
            for (int j = 0; j < 8; ++j) {
                const float w = A.inW[((s & 1) * 32 + quad * 8 + j) * H + n];
                const unsigned short hi = f2b(w);
                dst[j] = lo ? f2b(w - b2f(hi)) : hi;
            }
        }
    }
    grid.sync();

    // ---------- P1: input projection (MFMA) || ELL fill ----------
    for (int u = bid; u < NNODE / 64; u += GD) {
        const int mg = wv >> 1, nw = wv & 1;
        const int row0 = u * 64;
        bf16x8 fh[2][2], fl[2][2];
        #pragma unroll
        for (int mt = 0; mt < 2; ++mt) {
            const int row = row0 + (mg * 2 + mt) * 16 + col;
            #pragma unroll
            for (int j = 0; j < 2; ++j) {
                const float* src = &A.feats[(size_t)row * FIN + j * 32 + quad * 8];
                const float4 v0 = *(const float4*)src;
                const float4 v1 = *(const float4*)(src + 4);
                const float fv[8] = {v0.x, v0.y, v0.z, v0.w, v1.x, v1.y, v1.z, v1.w};
                union { bf16x8 v; unsigned short u16[8]; } Hh, Ll;
                #pragma unroll
                for (int q = 0; q < 8; ++q) {
                    const unsigned short hu = f2b(fv[q]);
                    Hh.u16[q] = hu;
                    Ll.u16[q] = f2b(fv[q] - b2f(hu));
                }
                fh[mt][j] = Hh.v;
                fl[mt][j] = Ll.v;
            }
        }
        f32x4 acc[2][4] = {};
        bf16x8 bC[4];
        #pragma unroll
        for (int nt = 0; nt < 4; ++nt)
            bC[nt] = *(const bf16x8*)&A.Bpi[((size_t)(nw * 4 + nt)) * 512 + lane * 8];
        #pragma unroll
        for (int s = 0; s < INSTEPS; ++s) {
            bf16x8 bN[4];
            if (s + 1 < INSTEPS) {
                #pragma unroll
                for (int nt = 0; nt < 4; ++nt)
                    bN[nt] = *(const bf16x8*)&A.Bpi[((size_t)(s + 1) * 8 + nw * 4 + nt) * 512 + lane * 8];
            }
            const int g = s >> 1, j = s & 1;
            #pragma unroll
            for (int mt = 0; mt < 2; ++mt) {
                const bf16x8 a = (g == 1) ? fl[mt][j] : fh[mt][j];
                #pragma unroll
                for (int nt = 0; nt < 4; ++nt)
                    acc[mt][nt] = __builtin_amdgcn_mfma_f32_16x16x32_bf16(a, bC[nt], acc[mt][nt], 0, 0, 0);
            }
            #pragma unroll
            for (int nt = 0; nt < 4; ++nt) bC[nt] = bN[nt];
        }
        #pragma unroll
        for (int nt = 0; nt < 4; ++nt) {
            const int hh = (nw * 4 + nt) * 16 + col;
            const float bv = A.inb[hh];
            #pragma unroll
            for (int mt = 0; mt < 2; ++mt)
                #pragma unroll
                for (int r = 0; r < 4; ++r) {
                    const int row = row0 + (mg * 2 + mt) * 16 + quad * 4 + r;
                    A.xh[(size_t)row * H + hh] = f2b(fmaxf(acc[mt][nt][r] + bv, 0.f));
                }
        }
    }
    for (int u = bid; u < (B * E) / 256; u += GD) {
        const int ge = u * 256 + tid;
        const float m = A.emask[ge];
        if (m > 0.f) {
            const int b = ge >> 16, e = ge & 0xFFFF;
            const int tgt = A.ei[(b * 2 + 1) * E + e];
            const int src = A.ei[(b * 2) * E + e];
            const int r = b * N + tgt;
            const int p = atomicAdd(&A.ecnt[r], 1);
            if (p < ELLW)
                A.ell[(size_t)r * ELLW + p] = ((unsigned int)f2b(m) << 16) | (unsigned int)src;
        }
    }
    grid.sync();

    // ---------- layers: [gather -> sync -> layer -> sync] x3 ----------
    const unsigned int* xh32 = (const unsigned int*)A.xh;
    unsigned int* nh32 = (unsigned int*)A.nh;
    for (int l = 0; l < NLAYER; ++l) {
        // gather
        for (int q = bid; q < NNODE / 4; q += GD) {
            const int b = q & 7;
            const int r = b * N + (q >> 3) * 4 + wv;
            unsigned int pv = 0;
            if (lane < ELLW) pv = A.ell[(size_t)r * ELLW + lane];
            const int cnt = min(A.ecnt[r], ELLW);
            if (lane >= cnt) pv = 0;
            const size_t bbase = (size_t)b * N * 64;
            float a0 = 0.f, a1 = 0.f, c = 0.f;
            const int cnt8 = (cnt + 7) & ~7;
            for (int jj = 0; jj < cnt8; jj += 8) {
                #pragma unroll
                for (int qq = 0; qq < 8; ++qq) {
                    const unsigned int pk = __shfl(pv, jj + qq);
                    const float m = b2f((unsigned short)(pk >> 16));
                    const unsigned int uu = xh32[bbase + (size_t)(pk & 0xFFFFu) * 64 + lane];
                    union { unsigned int i; float f; } lo, hi;
                    lo.i = uu << 16;
                    hi.i = uu & 0xFFFF0000u;
                    a0 = fmaf(lo.f, m, a0);
                    a1 = fmaf(hi.f, m, a1);
                    c += m;
                }
            }
            const float inv = 1.f / fmaxf(c, 1.f);
            nh32[(size_t)r * 64 + lane] = (unsigned int)f2b(a0 * inv) | ((unsigned int)f2b(a1 * inv) << 16);
        }
        grid.sync();

        // layer (LDS-staged B, 4 chunks; last layer emits pool partials)
        const unsigned short* Bpl = A.Bp + (size_t)l * BPL;
        const float* sb = A.selfb + l * H;
        const float* nb = A.neighb + l * H;
        const float* lg = A.lng + l * H;
        const float* lb = A.lnb + l * H;
        const int last = (l == NLAYER - 1);
        for (int u = bid; u < NNODE / 64; u += GD) {
            const int mg = wv >> 1, nw = wv & 1;
            const int b = u & 7;
            const int chunk = u >> 3;
            const int row0 = b * N + chunk * 64;
            size_t abase[2];
            #pragma unroll
            for (int mt = 0; mt < 2; ++mt)
                abase[mt] = (size_t)(row0 + (mg * 2 + mt) * 16 + col) * H + quad * 8;
            #pragma unroll
            for (int i = 0; i < 4; ++i) {
                const unsigned short* g = Bpl + (size_t)(wv * 4 + i) * 512 + lane * 8;
                __builtin_amdgcn_global_load_lds((const AS1 unsigned int*)g,
                                                 (AS3 unsigned int*)&bbuf[0][(wv * 4 + i) * 512],
                                                 16, 0, 0);
            }
            bf16x8 aC[2][2];
            #pragma unroll
            for (int j = 0; j < 2; ++j)
                #pragma unroll
                for (int mt = 0; mt < 2; ++mt)
                    aC[j][mt] = *(const bf16x8*)&A.xh[abase[mt] + j * 32];
            f32x4 acc[2][4] = {};
            #pragma unroll
            for (int c = 0; c < 4; ++c) {
                __syncthreads();
                bf16x8 aN[2][2];
                if (c < 3) {
                    const int c1 = c + 1;
                    #pragma unroll
                    for (int i = 0; i < 4; ++i) {
                        const unsigned short* g = Bpl + (size_t)(c1 * 16 + wv * 4 + i) * 512 + lane * 8;
                        __builtin_amdgcn_global_load_lds((const AS1 unsigned int*)g,
                                                         (AS3 unsigned int*)&bbuf[c1 & 1][(wv * 4 + i) * 512],
                                                         16, 0, 0);
                    }
                    const unsigned short* A1 = (c1 < 2) ? A.xh : A.nh;
                    #pragma unroll
                    for (int j = 0; j < 2; ++j)
                        #pragma unroll
                        for (int mt = 0; mt < 2; ++mt)
                            aN[j][mt] = *(const bf16x8*)&A1[abase[mt] + ((c1 & 1) * 2 + j) * 32];
                }
                #pragma unroll
                for (int j = 0; j < 2; ++j) {
                    bf16x8 bf[4];
                    #pragma unroll
                    for (int nt = 0; nt < 4; ++nt)
                        bf[nt] = *(const bf16x8*)&bbuf[c & 1][(j * 8 + nw * 4 + nt) * 512 + lane * 8];
                    #pragma unroll
                    for (int mt = 0; mt < 2; ++mt)
                        #pragma unroll
                        for (int nt = 0; nt < 4; ++nt)
                            acc[mt][nt] = __builtin_amdgcn_mfma_f32_16x16x32_bf16(aC[j][mt], bf[nt], acc[mt][nt], 0, 0, 0);
                }
                #pragma unroll
                for (int j = 0; j < 2; ++j)
                    #pragma unroll
                    for (int mt = 0; mt < 2; ++mt)
                        aC[j][mt] = aN[j][mt];
            }
            float sbv[4], nbv[4], gv[4], bbv[4];
            #pragma unroll
            for (int nt = 0; nt < 4; ++nt) {
                const int hh = (nw * 4 + nt) * 16 + col;
                sbv[nt] = sb[hh]; nbv[nt] = nb[hh]; gv[nt] = lg[hh]; bbv[nt] = lb[hh];
            }
            #pragma unroll
            for (int mt = 0; mt < 2; ++mt)
                #pragma unroll
                for (int nt = 0; nt < 4; ++nt)
                    #pragma unroll
                    for (int r = 0; r < 4; ++r)
                        acc[mt][nt][r] = fmaxf(acc[mt][nt][r] + sbv[nt] + nbv[nt], 0.f);
            #pragma unroll
            for (int mt = 0; mt < 2; ++mt)
                #pragma unroll
                for (int r = 0; r < 4; ++r) {
                    float p = 0.f, q = 0.f;
                    #pragma unroll
                    for (int nt = 0; nt < 4; ++nt) {
                        const float v = acc[mt][nt][r];
                        p += v;
                        q = fmaf(v, v, q);
                    }
                    p += __shfl_xor(p, 1);  q += __shfl_xor(q, 1);
                    p += __shfl_xor(p, 2);  q += __shfl_xor(q, 2);
                    p += __shfl_xor(p, 4);  q += __shfl_xor(q, 4);
                    p += __shfl_xor(p, 8);  q += __shfl_xor(q, 8);
                    if (col == 0) {
                        const int rib = (mg * 2 + mt) * 16 + quad * 4 + r;
                        lsum[nw][rib] = p;
                        lsq[nw][rib] = q;
                    }
                }
            __syncthreads();
            float psum[4] = {0.f, 0.f, 0.f, 0.f};
            float pmax[4] = {-INFINITY, -INFINITY, -INFINITY, -INFINITY};
            #pragma unroll
            for (int mt = 0; mt < 2; ++mt)
                #pragma unroll
                for (int r = 0; r < 4; ++r) {
                    const int rib = (mg * 2 + mt) * 16 + quad * 4 + r;
                    const int node = row0 + rib;
                    const float mu = (lsum[0][rib] + lsum[1][rib]) * (1.f / H);
                    const float var = (lsq[0][rib] + lsq[1][rib]) * (1.f / H) - mu * mu;
                    const float isd = rsqrtf(var + EPS);
                    const float m = A.nmask[node];
                    #pragma unroll
                    for (int nt = 0; nt < 4; ++nt) {
                        const float y = (fmaf(acc[mt][nt][r] - mu, isd * gv[nt], bbv[nt])) * m;
                        if (!last) {
                            A.xh[(size_t)node * H + (nw * 4 + nt) * 16 + col] = f2b(y);
                        } else {
                            psum[nt] += y;
                            pmax[nt] = fmaxf(pmax[nt], (m > 0.f) ? y : -INFINITY);
                        }
                    }
                }
            if (last) {
                #pragma unroll
                for (int nt = 0; nt < 4; ++nt) {
                    psum[nt] += __shfl_xor(psum[nt], 16);
                    psum[nt] += __shfl_xor(psum[nt], 32);
                    pmax[nt] = fmaxf(pmax[nt], __shfl_xor(pmax[nt], 16));
                    pmax[nt] = fmaxf(pmax[nt], __shfl_xor(pmax[nt], 32));
                }
                if (quad == 0)
                    #pragma unroll
                    for (int nt = 0; nt < 4; ++nt) {
                        psum_s[mg][(nw * 4 + nt) * 16 + col] = psum[nt];
                        pmax_s[mg][(nw * 4 + nt) * 16 + col] = pmax[nt];
                    }
                float nv = 0.f;
                if (wv == 0) {
                    nv = A.nmask[row0 + lane];
                    nv += __shfl_xor(nv, 1);  nv += __shfl_xor(nv, 2);
                    nv += __shfl_xor(nv, 4);  nv += __shfl_xor(nv, 8);
                    nv += __shfl_xor(nv, 16); nv += __shfl_xor(nv, 32);
                }
                __syncthreads();
                float* p = A.part + ((size_t)b * NCHUNK + chunk) * (2 * H + 1);
                if (tid < H) {
                    p[tid] = psum_s[0][tid] + psum_s[1][tid];
                    p[H + tid] = fmaxf(pmax_s[0][tid], pmax_s[1][tid]);
                }
                if (tid == 0) p[2 * H] = nv;
            }
        }
        grid.sync();
    }

    // ---------- P8: parallel pool-partial reduce (32 blocks) ----------
    if (bid < 32) {
        const int b = bid >> 2, sub = bid & 3;
        float acc = (tid < H) ? 0.f : -INFINITY;
        float nv = 0.f;
        for (int c = sub * (NCHUNK / 4); c < (sub + 1) * (NCHUNK / 4); ++c) {
            const float* p = A.part + ((size_t)b * NCHUNK + c) * (2 * H + 1);
            if (tid < H) acc += p[tid];
            else acc = fmaxf(acc, p[tid]);
            if (tid == 0) nv += p[2 * H];
        }
        float* q = A.part2 + (size_t)(b * 4 + sub) * 258;
        q[tid] = acc;
        if (tid == 0) q[256] = nv;
    }
    grid.sync();

    // ---------- P9: MLP head (8 blocks) ----------
    if (bid < 8) {
        const int b = bid;
        float* g = (float*)&bbuf[0][0];          // 256 floats
        float* hid = g + 272;
        const float* q0 = A.part2 + (size_t)(b * 4 + 0) * 258;
        const float* q1 = A.part2 + (size_t)(b * 4 + 1) * 258;
        const float* q2 = A.part2 + (size_t)(b * 4 + 2) * 258;
        const float* q3 = A.part2 + (size_t)(b * 4 + 3) * 258;
        const float nv = fmaxf(q0[256] + q1[256] + q2[256] + q3[256], 1.f);
        if (tid < H)
            g[tid] = (q0[tid] + q1[tid] + q2[tid] + q3[tid]) / nv;
        else
            g[tid] = fmaxf(fmaxf(q0[tid], q1[tid]), fmaxf(q2[tid], q3[tid]));
        __syncthreads();
        if (tid < H) {
            float a = A.b1[tid];
            #pragma unroll 8
            for (int k = 0; k < 2 * H; ++k) a = fmaf(g[k], A.W1[k * H + tid], a);
            hid[tid] = fmaxf(a, 0.f);
        }
        __syncthreads();
        float a = A.b2[tid];
        #pragma unroll 8
        for (int k = 0; k < H; ++k) a = fmaf(hid[k], A.W2[k * OUTD + tid], a);
        A.out[(size_t)b * OUTD + tid] = a;
    }
}

// ==================== fallback kernels (r13 path, proven at 253 us) ====================
__global__ void k_prep(const float* __restrict__ selfW, const float* __restrict__ neighW,
                       const float* __restrict__ inW,
                       unsigned short* __restrict__ Bp, unsigned short* __restrict__ Bpi) {
    const int idx = blockIdx.x;
    const int lane = threadIdx.x;
    const int quad = lane >> 4, col = lane & 15;
    if (idx < NLAYER * KSTEPS * 8) {
        const int t = idx & 7;
        const int s = (idx >> 3) % KSTEPS;
        const int l = idx / (KSTEPS * 8);
        const float* W = (((s >> 2) == 0) ? selfW : neighW) + (size_t)l * H * H;
        const int n = t * 16 + col;
        unsigned short* dst = Bp + ((size_t)(l * KSTEPS + s) * 8 + t) * 512 + lane * 8;
        #pragma unroll
        for (int j = 0; j < 8; ++j)
            dst[j] = f2b(W[((s & 3) * 32 + quad * 8 + j) * H + n]);
    } else {
        const int idx2 = idx - NLAYER * KSTEPS * 8;
        const int t = idx2 & 7;
        const int s = idx2 >> 3;
        const bool lo = ((s >> 1) == 2);
        const int n = t * 16 + col;
        unsigned short* dst = Bpi + ((size_t)(s * 8 + t)) * 512 + lane * 8;
        #pragma unroll
        for (int j = 0; j < 8; ++j) {
            const float w = inW[((s & 1) * 32 + quad * 8 + j) * H + n];
            const unsigned short hi = f2b(w);
            dst[j] = lo ? f2b(w - b2f(hi)) : hi;
        }
    }
}

__global__ __launch_bounds__(256) void k_front(const float* __restrict__ feats,
                                               const unsigned short* __restrict__ Bpi,
                                               const float* __restrict__ bias,
                                               unsigned short* __restrict__ xh,
                                               const int* __restrict__ ei,
                                               const float* __restrict__ emask,
                                               int* __restrict__ ecnt,
                                               unsigned int* __restrict__ ell) {
    const int tid = threadIdx.x;
    if (blockIdx.x >= 1024) {
        const int ge = (blockIdx.x - 1024) * 256 + tid;
        const float m = emask[ge];
        if (m > 0.f) {
            const int b = ge >> 16, e = ge & 0xFFFF;
            const int tgt = ei[(b * 2 + 1) * E + e];
            const int src = ei[(b * 2) * E + e];
            const int r = b * N + tgt;
            const int p = atomicAdd(&ecnt[r], 1);
            if (p < ELLW)
                ell[(size_t)r * ELLW + p] = ((unsigned int)f2b(m) << 16) | (unsigned int)src;
        }
        return;
    }
    const int wv = tid >> 6, lane = tid & 63;
    const int quad = lane >> 4, col = lane & 15;
    const int mg = wv >> 1, nw = wv & 1;
    const int row0 = blockIdx.x * 64;
    bf16x8 fh[2][2], fl[2][2];
    #pragma unroll
    for (int mt = 0; mt < 2; ++mt) {
        const int row = row0 + (mg * 2 + mt) * 16 + col;
        #pragma unroll
        for (int j = 0; j < 2; ++j) {
            const float* src = &feats[(size_t)row * FIN + j * 32 + quad * 8];
            const float4 v0 = *(const float4*)src;
            const float4 v1 = *(const float4*)(src + 4);
            const float fv[8] = {v0.x, v0.y, v0.z, v0.w, v1.x, v1.y, v1.z, v1.w};
            union { bf16x8 v; unsigned short u[8]; } Hh, Ll;
            #pragma unroll
            for (int q = 0; q < 8; ++q) {
                const unsigned short hu = f2b(fv[q]);
                Hh.u[q] = hu;
                Ll.u[q] = f2b(fv[q] - b2f(hu));
            }
            fh[mt][j] = Hh.v;
            fl[mt][j] = Ll.v;
        }
    }
    f32x4 acc[2][4] = {};
    bf16x8 bC[4];
    #pragma unroll
    for (int nt = 0; nt < 4; ++nt)
        bC[nt] = *(const bf16x8*)&Bpi[((size_t)(nw * 4 + nt)) * 512 + lane * 8];
    #pragma unroll
    for (int s = 0; s < INSTEPS; ++s) {
        bf16x8 bN[4];
        if (s + 1 < INSTEPS) {
            #pragma unroll
            for (int nt = 0; nt < 4; ++nt)
                bN[nt] = *(const bf16x8*)&Bpi[((size_t)(s + 1) * 8 + nw * 4 + nt) * 512 + lane * 8];
        }
        const int g = s >> 1, j = s & 1;
        #pragma unroll
        for (int mt = 0; mt < 2; ++mt) {
            const bf16x8 a = (g == 1) ? fl[mt][j] : fh[mt][j];
            #pragma unroll
            for (int nt = 0; nt < 4; ++nt)
                acc[mt][nt] = __builtin_amdgcn_mfma_f32_16x16x32_bf16(a, bC[nt], acc[mt][nt], 0, 0, 0);
        }
        #pragma unroll
        for (int nt = 0; nt < 4; ++nt) bC[nt] = bN[nt];
    }
    #pragma unroll
    for (int nt = 0; nt < 4; ++nt) {
        const int hh = (nw * 4 + nt) * 16 + col;
        const float bv = bias[hh];
        #pragma unroll
        for (int mt = 0; mt < 2; ++mt)
            #pragma unroll
            for (int r = 0; r < 4; ++r) {
                const int row = row0 + (mg * 2 + mt) * 16 + quad * 4 + r;
                xh[(size_t)row * H + hh] = f2b(fmaxf(acc[mt][nt][r] + bv, 0.f));
            }
    }
}

__global__ __launch_bounds__(256) void k_gather7(const unsigned int* __restrict__ xh32,
                                                 const int* __restrict__ ecnt,
                                                 const unsigned int* __restrict__ ell,
                                                 unsigned int* __restrict__ nh32) {
    const int beta = blockIdx.x;
    const int b = beta & 7;
    const int grp = beta >> 3;
    const int wave = threadIdx.x >> 6, lane = threadIdx.x & 63;
    const int r = b * N + grp * 4 + wave;
    unsigned int pv = 0;
    if (lane < ELLW) pv = ell[(size_t)r * ELLW + lane];
    const int cnt = min(ecnt[r], ELLW);
    if (lane >= cnt) pv = 0;
    const size_t bbase = (size_t)b * N * 64;
    float a0 = 0.f, a1 = 0.f, c = 0.f;
    const int cnt8 = (cnt + 7) & ~7;
    for (int jj = 0; jj < cnt8; jj += 8) {
        #pragma unroll
        for (int q = 0; q < 8; ++q) {
            const unsigned int pk = __shfl(pv, jj + q);
            const float m = b2f((unsigned short)(pk >> 16));
            const unsigned int u = xh32[bbase + (size_t)(pk & 0xFFFFu) * 64 + lane];
            union { unsigned int i; float f; } lo, hi;
            lo.i = u << 16;
            hi.i = u & 0xFFFF0000u;
            a0 = fmaf(lo.f, m, a0);
            a1 = fmaf(hi.f, m, a1);
            c += m;
        }
    }
    const float inv = 1.f / fmaxf(c, 1.f);
    nh32[(size_t)r * 64 + lane] = (unsigned int)f2b(a0 * inv) | ((unsigned int)f2b(a1 * inv) << 16);
}

__global__ __launch_bounds__(256) void k_layer9(const unsigned short* __restrict__ xinh,
                                                const unsigned short* __restrict__ nh,
                                                const unsigned short* __restrict__ Bp,
                                                const float* __restrict__ sb,
                                                const float* __restrict__ nb,
                                                const float* __restrict__ lng,
                                                const float* __restrict__ lnb,
                                                const float* __restrict__ nmask,
                                                unsigned short* __restrict__ oxh,
                                                float* __restrict__ part,
                                                const int last) {
    __shared__ __align__(16) unsigned short bbuf[2][16 * 512];
    __shared__ float lsum[2][64];
    __shared__ float lsq[2][64];
    __shared__ float psum_s[2][H];
    __shared__ float pmax_s[2][H];
    const int tid = threadIdx.x;
    const int wv = tid >> 6, lane = tid & 63;
    const int quad = lane >> 4, col = lane & 15;
    const int mg = wv >> 1, nw = wv & 1;
    const int u = blockIdx.x;
    const int b = u & 7;
    const int chunk = u >> 3;
    const int row0 = b * N + chunk * 64;
    size_t abase[2];
    #pragma unroll
    for (int mt = 0; mt < 2; ++mt)
        abase[mt] = (size_t)(row0 + (mg * 2 + mt) * 16 + col) * H + quad * 8;
    #pragma unroll
    for (int i = 0; i < 4; ++i) {
        const unsigned short* g = Bp + (size_t)(wv * 4 + i) * 512 + lane * 8;
        __builtin_amdgcn_global_load_lds((const AS1 unsigned int*)g,
                                         (AS3 unsigned int*)&bbuf[0][(wv * 4 + i) * 512],
                                         16, 0, 0);
    }
    bf16x8 aC[2][2];
    #pragma unroll
    for (int j = 0; j < 2; ++j)
        #pragma unroll
        for (int mt = 0; mt < 2; ++mt)
            aC[j][mt] = *(const bf16x8*)&xinh[abase[mt] + j * 32];
    f32x4 acc[2][4] = {};
    #pragma unroll
    for (int c = 0; c < 4; ++c) {
        __syncthreads();
        bf16x8 aN[2][2];
        if (c < 3) {
            const int c1 = c + 1;
            #pragma unroll
            for (int i = 0; i < 4; ++i) {
                const unsigned short* g = Bp + (size_t)(c1 * 16 + wv * 4 + i) * 512 + lane * 8;
                __builtin_amdgcn_global_load_lds((const AS1 unsigned int*)g,
                                                 (AS3 unsigned int*)&bbuf[c1 & 1][(wv * 4 + i) * 512],
                                                 16, 0, 0);
            }
            const unsigned short* A1 = (c1 < 2) ? xinh : nh;
            #pragma unroll
            for (int j = 0; j < 2; ++j)
                #pragma unroll
                for (int mt = 0; mt < 2; ++mt)
                    aN[j][mt] = *(const bf16x8*)&A1[abase[mt] + ((c1 & 1) * 2 + j) * 32];
        }
        #pragma unroll
        for (int j = 0; j < 2; ++j) {
            bf16x8 bf[4];
            #pragma unroll
            for (int nt = 0; nt < 4; ++nt)
                bf[nt] = *(const bf16x8*)&bbuf[c & 1][(j * 8 + nw * 4 + nt) * 512 + lane * 8];
            #pragma unroll
            for (int mt = 0; mt < 2; ++mt)
                #pragma unroll
                for (int nt = 0; nt < 4; ++nt)
                    acc[mt][nt] = __builtin_amdgcn_mfma_f32_16x16x32_bf16(aC[j][mt], bf[nt], acc[mt][nt], 0, 0, 0);
        }
        #pragma unroll
        for (int j = 0; j < 2; ++j)
            #pragma unroll
            for (int mt = 0; mt < 2; ++mt)
                aC[j][mt] = aN[j][mt];
    }
    float sbv[4], nbv[4], gv[4], bbv[4];
    #pragma unroll
    for (int nt = 0; nt < 4; ++nt) {
        const int hh = (nw * 4 + nt) * 16 + col;
        sbv[nt] = sb[hh]; nbv[nt] = nb[hh]; gv[nt] = lng[hh]; bbv[nt] = lnb[hh];
    }
    #pragma unroll
    for (int mt = 0; mt < 2; ++mt)
        #pragma unroll
        for (int nt = 0; nt < 4; ++nt)
            #pragma unroll
            for (int r = 0; r < 4; ++r)
                acc[mt][nt][r] = fmaxf(acc[mt][nt][r] + sbv[nt] + nbv[nt], 0.f);
    #pragma unroll
    for (int mt = 0; mt < 2; ++mt)
        #pragma unroll
        for (int r = 0; r < 4; ++r) {
            float p = 0.f, q = 0.f;
            #pragma unroll
            for (int nt = 0; nt < 4; ++nt) {
                const float v = acc[mt][nt][r];
                p += v;
                q = fmaf(v, v, q);
            }
            p += __shfl_xor(p, 1);  q += __shfl_xor(q, 1);
            p += __shfl_xor(p, 2);  q += __shfl_xor(q, 2);
            p += __shfl_xor(p, 4);  q += __shfl_xor(q, 4);
            p += __shfl_xor(p, 8);  q += __shfl_xor(q, 8);
            if (col == 0) {
                const int rib = (mg * 2 + mt) * 16 + quad * 4 + r;
                lsum[nw][rib] = p;
                lsq[nw][rib] = q;
            }
        }
    __syncthreads();
    float psum[4] = {0.f, 0.f, 0.f, 0.f};
    float pmax[4] = {-INFINITY, -INFINITY, -INFINITY, -INFINITY};
    #pragma unroll
    for (int mt = 0; mt < 2; ++mt)
        #pragma unroll
        for (int r = 0; r < 4; ++r) {
            const int rib = (mg * 2 + mt) * 16 + quad * 4 + r;
            const int node = row0 + rib;
            const float mu = (lsum[0][rib] + lsum[1][rib]) * (1.f / H);
            const float var = (lsq[0][rib] + lsq[1][rib]) * (1.f / H) - mu * mu;
            const float isd = rsqrtf(var + EPS);
            const float m = nmask[node];
            #pragma unroll
            for (int nt = 0; nt < 4; ++nt) {
                const float y = (fmaf(acc[mt][nt][r] - mu, isd * gv[nt], bbv[nt])) * m;
                if (!last) {
                    oxh[(size_t)node * H + (nw * 4 + nt) * 16 + col] = f2b(y);
                } else {
                    psum[nt] += y;
                    pmax[nt] = fmaxf(pmax[nt], (m > 0.f) ? y : -INFINITY);
                }
            }
        }
    if (last) {
        #pragma unroll
        for (int nt = 0; nt < 4; ++nt) {
            psum[nt] += __shfl_xor(psum[nt], 16);
            psum[nt] += __shfl_xor(psum[nt], 32);
            pmax[nt] = fmaxf(pmax[nt], __shfl_xor(pmax[nt], 16));
            pmax[nt] = fmaxf(pmax[nt], __shfl_xor(pmax[nt], 32));
        }
        if (quad == 0)
            #pragma unroll
            for (int nt = 0; nt < 4; ++nt) {
                psum_s[mg][(nw * 4 + nt) * 16 + col] = psum[nt];
                pmax_s[mg][(nw * 4 + nt) * 16 + col] = pmax[nt];
            }
        float nv = 0.f;
        if (wv == 0) {
            nv = nmask[row0 + lane];
            nv += __shfl_xor(nv, 1);  nv += __shfl_xor(nv, 2);
            nv += __shfl_xor(nv, 4);  nv += __shfl_xor(nv, 8);
            nv += __shfl_xor(nv, 16); nv += __shfl_xor(nv, 32);
        }
        __syncthreads();
        float* p = part + ((size_t)b * NCHUNK + chunk) * (2 * H + 1);
        if (tid < H) {
            p[tid] = psum_s[0][tid] + psum_s[1][tid];
            p[H + tid] = fmaxf(pmax_s[0][tid], pmax_s[1][tid]);
        }
        if (tid == 0) p[2 * H] = nv;
    }
}

__global__ __launch_bounds__(1024) void k_tail2(const float* __restrict__ part,
                                                const float* __restrict__ W1, const float* __restrict__ b1,
                                                const float* __restrict__ W2, const float* __restrict__ b2,
                                                float* __restrict__ out) {
    const int b = blockIdx.x, tid = threadIdx.x;
    const int col = tid & 255;
    const int sub = tid >> 8;
    __shared__ float sred[4][2 * H];
    __shared__ float nvl[NCHUNK];
    __shared__ float g[2 * H];
    __shared__ float hid[H];
    {
        float acc = (col < H) ? 0.f : -INFINITY;
        #pragma unroll 8
        for (int c = sub * (NCHUNK / 4); c < (sub + 1) * (NCHUNK / 4); ++c) {
            const float v = part[((size_t)b * NCHUNK + c) * (2 * H + 1) + col];
            acc = (col < H) ? (acc + v) : fmaxf(acc, v);
        }
        sred[sub][col] = acc;
    }
    if (tid < NCHUNK)
        nvl[tid] = part[((size_t)b * NCHUNK + tid) * (2 * H + 1) + 2 * H];
    __syncthreads();
    for (int s = NCHUNK / 2; s > 0; s >>= 1) {
        if (tid < s) nvl[tid] += nvl[tid + s];
        __syncthreads();
    }
    const float nv = fmaxf(nvl[0], 1.f);
    if (tid < 2 * H) {
        if (tid < H)
            g[tid] = (sred[0][tid] + sred[1][tid] + sred[2][tid] + sred[3][tid]) / nv;
        else
            g[tid] = fmaxf(fmaxf(sred[0][tid], sred[1][tid]), fmaxf(sred[2][tid], sred[3][tid]));
    }
    __syncthreads();
    if (tid < H) {
        float a = b1[tid];
        #pragma unroll 8
        for (int k = 0; k < 2 * H; ++k) a = fmaf(g[k], W1[k * H + tid], a);
        hid[tid] = fmaxf(a, 0.f);
    }
    __syncthreads();
    if (tid < OUTD) {
        float a = b2[tid];
        #pragma unroll 8
        for (int k = 0; k < H; ++k) a = fmaf(hid[k], W2[k * OUTD + tid], a);
        out[(size_t)b * OUTD + tid] = a;
    }
}

extern "C" void kernel_launch(void* const* d_in, const int* in_sizes, int n_in,
                              void* d_out, int out_size, void* d_ws, size_t ws_size,
                              hipStream_t stream) {
    const float* feats = (const float*)d_in[0];
    const int*   ei    = (const int*)d_in[1];
    const float* nmask = (const float*)d_in[2];
    const float* emask = (const float*)d_in[3];
    const float* inW   = (const float*)d_in[4];
    const float* inb   = (const float*)d_in[5];
    const float* selfW = (const float*)d_in[6];
    const float* selfb = (const float*)d_in[7];
    const float* neighW= (const float*)d_in[8];
    const float* neighb= (const float*)d_in[9];
    const float* lng   = (const float*)d_in[10];
    const float* lnb   = (const float*)d_in[11];
    const float* W1    = (const float*)d_in[12];
    const float* b1    = (const float*)d_in[13];
    const float* W2    = (const float*)d_in[14];
    const float* b2    = (const float*)d_in[15];
    float* out = (float*)d_out;

    const size_t nxh = (size_t)NNODE * H;
    char* w = (char*)d_ws;
    unsigned short* xh  = (unsigned short*)w;  w += nxh * 2;
    unsigned short* nh  = (unsigned short*)w;  w += nxh * 2;
    unsigned short* Bp  = (unsigned short*)w;  w += (size_t)NLAYER * BPL * 2;
    unsigned short* Bpi = (unsigned short*)w;  w += (size_t)INSTEPS * 8 * 512 * 2;
    float* part  = (float*)w;                  w += (size_t)B * NCHUNK * (2 * H + 1) * 4;
    float* part2 = (float*)w;                  w += (size_t)32 * 258 * 4;
    int* ecnt   = (int*)w;                     w += (size_t)NNODE * 4;
    unsigned int* ell = (unsigned int*)w;      w += (size_t)NNODE * ELLW * 4;

    // ---- cooperative single-launch path ----
    int maxB = 0;
    hipError_t qerr = hipOccupancyMaxActiveBlocksPerMultiprocessor(&maxB, k_mega, 256, 0);
    int grid = (qerr == hipSuccess) ? maxB * 256 : 0;   // 256 CUs on MI355X
    if (grid > 1024) grid = 1024;
    grid &= ~7;                                          // preserve batch<->XCD pinning
    bool coop = (grid >= 64);
    if (coop) {
        MegaArgs A;
        A.feats = feats; A.ei = ei; A.nmask = nmask; A.emask = emask;
        A.inW = inW; A.inb = inb; A.selfW = selfW; A.selfb = selfb;
        A.neighW = neighW; A.neighb = neighb; A.lng = lng; A.lnb = lnb;
        A.W1 = W1; A.b1 = b1; A.W2 = W2; A.b2 = b2;
        A.out = out;
        A.xh = xh; A.nh = nh; A.Bp = Bp; A.Bpi = Bpi;
        A.part = part; A.part2 = part2;
        A.ecnt = ecnt; A.ell = ell;
        void* kargs[] = {&A};
        hipError_t err = hipLaunchCooperativeKernel((const void*)k_mega, dim3(grid), dim3(256),
                                                    kargs, 0, stream);
        coop = (err == hipSuccess);
    }
    if (coop) return;

    // ---- fallback: proven r13 multi-launch path ----
    k_prep<<<NLAYER * KSTEPS * 8 + INSTEPS * 8, 64, 0, stream>>>(selfW, neighW, inW, Bp, Bpi);
    hipMemsetAsync(ecnt, 0, (size_t)NNODE * sizeof(int), stream);
    k_front<<<1024 + B * E / 256, 256, 0, stream>>>(feats, Bpi, inb, xh, ei, emask, ecnt, ell);
    for (int l = 0; l < NLAYER; ++l) {
        k_gather7<<<NNODE / 4, 256, 0, stream>>>((const unsigned int*)xh, ecnt, ell,
                                                 (unsigned int*)nh);
        k_layer9<<<NNODE / 64, 256, 0, stream>>>(xh, nh,
                                                 Bp + (size_t)l * BPL,
                                                 selfb + (size_t)l * H, neighb + (size_t)l * H,
                                                 lng + (size_t)l * H, lnb + (size_t)l * H,
                                                 nmask, xh, part, (l == NLAYER - 1) ? 1 : 0);
    }
    k_tail2<<<B, 1024, 0, stream>>>(part, W1, b1, W2, b2, out);
}

// Round 15
// 338.040 us; speedup vs baseline: 2.6820x; 2.6820x over previous
//
#include <hip/hip_runtime.h>
#include <hip/hip_bf16.h>

#define B 8
#define N 8192
#define E 65536
#define FIN 64
#define H 128
#define OUTD 256
#define NLAYER 3
#define EPS 1e-5f
#define NCHUNK 128               // pool chunks per batch (one per 64-row layer block)
#define NNODE (B * N)            // 65536 rows
#define KSTEPS 8                 // 2 groups x 4 k-steps of K=32 (xh*sWhi, nh*nWhi)
#define BPL (KSTEPS * 8 * 512)   // Bp ushort elems per layer
#define INSTEPS 6                // inproj: 3 groups x 2 k-steps (fh*Whi, fl*Whi, fh*Wlo)
#define ELLW 48                  // max incoming edges/node (Poisson(8): P(>48) ~ 1e-25)
#define PREPN (NLAYER * KSTEPS * 8 + INSTEPS * 8)   // 240 prep blocks
#define LGRID (NNODE / 64)       // 1024 layer blocks

#define AS1 __attribute__((address_space(1)))
#define AS3 __attribute__((address_space(3)))

typedef float f32x4 __attribute__((ext_vector_type(4)));
typedef __bf16 bf16x8 __attribute__((ext_vector_type(8)));

__device__ __forceinline__ float b2f(unsigned short u) {
    union { float f; unsigned int i; } c; c.i = ((unsigned int)u) << 16; return c.f;
}
__device__ __forceinline__ unsigned short f2b(float f) {
    __hip_bfloat16 h = __float2bfloat16(f);          // RTNE
    return *reinterpret_cast<unsigned short*>(&h);
}

// ---------------- weight pre-pack + ecnt/ctr zeroing (one node) ----------------
// blocks [0,240): pack Bp/Bpi; blocks [240, 240+1024): zero ecnt (+ctr once)
__global__ void k_prep(const float* __restrict__ selfW, const float* __restrict__ neighW,
                       const float* __restrict__ inW,
                       unsigned short* __restrict__ Bp, unsigned short* __restrict__ Bpi,
                       int* __restrict__ ecnt, int* __restrict__ ctr) {
    const int idx = blockIdx.x;
    const int lane = threadIdx.x;
    const int quad = lane >> 4, col = lane & 15;
    if (idx >= PREPN) {
        ecnt[(idx - PREPN) * 64 + lane] = 0;
        if (idx == PREPN && lane == 0) *ctr = 0;
        return;
    }
    if (idx < NLAYER * KSTEPS * 8) {
        const int t = idx & 7;
        const int s = (idx >> 3) % KSTEPS;
        const int l = idx / (KSTEPS * 8);
        const float* W = (((s >> 2) == 0) ? selfW : neighW) + (size_t)l * H * H;
        const int n = t * 16 + col;
        unsigned short* dst = Bp + ((size_t)(l * KSTEPS + s) * 8 + t) * 512 + lane * 8;
        #pragma unroll
        for (int j = 0; j < 8; ++j)
            dst[j] = f2b(W[((s & 3) * 32 + quad * 8 + j) * H + n]);
    } else {
        const int idx2 = idx - NLAYER * KSTEPS * 8;
        const int t = idx2 & 7;
        const int s = idx2 >> 3;                     // 0..5
        const bool lo = ((s >> 1) == 2);
        const int n = t * 16 + col;
        unsigned short* dst = Bpi + ((size_t)(s * 8 + t)) * 512 + lane * 8;
        #pragma unroll
        for (int j = 0; j < 8; ++j) {
            const float w = inW[((s & 1) * 32 + quad * 8 + j) * H + n];
            const unsigned short hi = f2b(w);
            dst[j] = lo ? f2b(w - b2f(hi)) : hi;
        }
    }
}

// ---------------- fat kernel: inproj (blocks 0..1023) || ELL fill (blocks 1024..3071) ----------------
__global__ __launch_bounds__(256) void k_front(const float* __restrict__ feats,
                                               const unsigned short* __restrict__ Bpi,
                                               const float* __restrict__ bias,
                                               unsigned short* __restrict__ xh,
                                               const int* __restrict__ ei,
                                               const float* __restrict__ emask,
                                               int* __restrict__ ecnt,
                                               unsigned int* __restrict__ ell) {
    const int tid = threadIdx.x;
    if (blockIdx.x >= 1024) {
        const int ge = (blockIdx.x - 1024) * 256 + tid;      // b*E + e
        const float m = emask[ge];
        if (m > 0.f) {
            const int b = ge >> 16, e = ge & 0xFFFF;
            const int tgt = ei[(b * 2 + 1) * E + e];
            const int src = ei[(b * 2) * E + e];
            const int r = b * N + tgt;
            const int p = atomicAdd(&ecnt[r], 1);
            if (p < ELLW)
                ell[(size_t)r * ELLW + p] = ((unsigned int)f2b(m) << 16) | (unsigned int)src;
        }
        return;
    }
    const int wv = tid >> 6, lane = tid & 63;
    const int quad = lane >> 4, col = lane & 15;
    const int mg = wv >> 1, nw = wv & 1;
    const int row0 = blockIdx.x * 64;
    bf16x8 fh[2][2], fl[2][2];
    #pragma unroll
    for (int mt = 0; mt < 2; ++mt) {
        const int row = row0 + (mg * 2 + mt) * 16 + col;
        #pragma unroll
        for (int j = 0; j < 2; ++j) {
            const float* src = &feats[(size_t)row * FIN + j * 32 + quad * 8];
            const float4 v0 = *(const float4*)src;
            const float4 v1 = *(const float4*)(src + 4);
            const float fv[8] = {v0.x, v0.y, v0.z, v0.w, v1.x, v1.y, v1.z, v1.w};
            union { bf16x8 v; unsigned short u[8]; } Hh, Ll;
            #pragma unroll
            for (int q = 0; q < 8; ++q) {
                const unsigned short hu = f2b(fv[q]);
                Hh.u[q] = hu;
                Ll.u[q] = f2b(fv[q] - b2f(hu));
            }
            fh[mt][j] = Hh.v;
            fl[mt][j] = Ll.v;
        }
    }
    f32x4 acc[2][4] = {};
    bf16x8 bC[4];
    #pragma unroll
    for (int nt = 0; nt < 4; ++nt)
        bC[nt] = *(const bf16x8*)&Bpi[((size_t)(nw * 4 + nt)) * 512 + lane * 8];
    #pragma unroll
    for (int s = 0; s < INSTEPS; ++s) {
        bf16x8 bN[4];
        if (s + 1 < INSTEPS) {
            #pragma unroll
            for (int nt = 0; nt < 4; ++nt)
                bN[nt] = *(const bf16x8*)&Bpi[((size_t)(s + 1) * 8 + nw * 4 + nt) * 512 + lane * 8];
        }
        const int g = s >> 1, j = s & 1;
        #pragma unroll
        for (int mt = 0; mt < 2; ++mt) {
            const bf16x8 a = (g == 1) ? fl[mt][j] : fh[mt][j];
            #pragma unroll
            for (int nt = 0; nt < 4; ++nt)
                acc[mt][nt] = __builtin_amdgcn_mfma_f32_16x16x32_bf16(a, bC[nt], acc[mt][nt], 0, 0, 0);
        }
        #pragma unroll
        for (int nt = 0; nt < 4; ++nt) bC[nt] = bN[nt];
    }
    #pragma unroll
    for (int nt = 0; nt < 4; ++nt) {
        const int hh = (nw * 4 + nt) * 16 + col;
        const float bv = bias[hh];
        #pragma unroll
        for (int mt = 0; mt < 2; ++mt)
            #pragma unroll
            for (int r = 0; r < 4; ++r) {
                const int row = row0 + (mg * 2 + mt) * 16 + quad * 4 + r;
                xh[(size_t)row * H + hh] = f2b(fmaxf(acc[mt][nt][r] + bv, 0.f));
            }
    }
}

// ---------------- gather: speculative ELL read, unroll-8, one wave per row ----------------
__global__ __launch_bounds__(256) void k_gather7(const unsigned int* __restrict__ xh32,
                                                 const int* __restrict__ ecnt,
                                                 const unsigned int* __restrict__ ell,
                                                 unsigned int* __restrict__ nh32) {
    const int beta = blockIdx.x;               // 0..16383
    const int b = beta & 7;
    const int grp = beta >> 3;
    const int wave = threadIdx.x >> 6, lane = threadIdx.x & 63;
    const int r = b * N + grp * 4 + wave;
    unsigned int pv = 0;
    if (lane < ELLW) pv = ell[(size_t)r * ELLW + lane];
    const int cnt = min(ecnt[r], ELLW);
    if (lane >= cnt) pv = 0;
    const size_t bbase = (size_t)b * N * 64;
    float a0 = 0.f, a1 = 0.f, c = 0.f;
    const int cnt8 = (cnt + 7) & ~7;
    for (int jj = 0; jj < cnt8; jj += 8) {
        #pragma unroll
        for (int q = 0; q < 8; ++q) {
            const unsigned int pk = __shfl(pv, jj + q);
            const float m = b2f((unsigned short)(pk >> 16));
            const unsigned int u = xh32[bbase + (size_t)(pk & 0xFFFFu) * 64 + lane];
            union { unsigned int i; float f; } lo, hi;
            lo.i = u << 16;
            hi.i = u & 0xFFFF0000u;
            a0 = fmaf(lo.f, m, a0);
            a1 = fmaf(hi.f, m, a1);
            c += m;
        }
    }
    const float inv = 1.f / fmaxf(c, 1.f);
    nh32[(size_t)r * 64 + lane] = (unsigned int)f2b(a0 * inv) | ((unsigned int)f2b(a1 * inv) << 16);
}

// ---------------- fused layer: LDS-staged B; last layer emits pool partials + finisher tail ----------------
__global__ __launch_bounds__(256) void k_layer10(const unsigned short* __restrict__ xinh,
                                                 const unsigned short* __restrict__ nh,
                                                 const unsigned short* __restrict__ Bp,
                                                 const float* __restrict__ sb,
                                                 const float* __restrict__ nb,
                                                 const float* __restrict__ lng,
                                                 const float* __restrict__ lnb,
                                                 const float* __restrict__ nmask,
                                                 unsigned short* __restrict__ oxh,
                                                 float* __restrict__ part,
                                                 const float* __restrict__ W1, const float* __restrict__ b1,
                                                 const float* __restrict__ W2, const float* __restrict__ b2,
                                                 float* __restrict__ out,
                                                 int* __restrict__ ctr,
                                                 const int last) {
    __shared__ __align__(16) unsigned short bbuf[2][16 * 512];   // 2 x 16 KB
    __shared__ float lsum[2][64];
    __shared__ float lsq[2][64];
    __shared__ float psum_s[2][H];
    __shared__ float pmax_s[2][H];
    __shared__ float nvl[NCHUNK];
    __shared__ int tick_s;

    const int tid = threadIdx.x;
    const int wv = tid >> 6, lane = tid & 63;
    const int quad = lane >> 4, col = lane & 15;
    const int mg = wv >> 1, nw = wv & 1;
    const int u = blockIdx.x;
    const int b = u & 7;
    const int chunk = u >> 3;                     // 0..127
    const int row0 = b * N + chunk * 64;          // batch-pinned to XCD b

    size_t abase[2];
    #pragma unroll
    for (int mt = 0; mt < 2; ++mt)
        abase[mt] = (size_t)(row0 + (mg * 2 + mt) * 16 + col) * H + quad * 8;

    #pragma unroll
    for (int i = 0; i < 4; ++i) {
        const unsigned short* g = Bp + (size_t)(wv * 4 + i) * 512 + lane * 8;
        __builtin_amdgcn_global_load_lds((const AS1 unsigned int*)g,
                                         (AS3 unsigned int*)&bbuf[0][(wv * 4 + i) * 512],
                                         16, 0, 0);
    }
    bf16x8 aC[2][2];
    #pragma unroll
    for (int j = 0; j < 2; ++j)
        #pragma unroll
        for (int mt = 0; mt < 2; ++mt)
            aC[j][mt] = *(const bf16x8*)&xinh[abase[mt] + j * 32];

    f32x4 acc[2][4] = {};

    #pragma unroll
    for (int c = 0; c < 4; ++c) {
        __syncthreads();
        bf16x8 aN[2][2];
        if (c < 3) {
            const int c1 = c + 1;
            #pragma unroll
            for (int i = 0; i < 4; ++i) {
                const unsigned short* g = Bp + (size_t)(c1 * 16 + wv * 4 + i) * 512 + lane * 8;
                __builtin_amdgcn_global_load_lds((const AS1 unsigned int*)g,
                                                 (AS3 unsigned int*)&bbuf[c1 & 1][(wv * 4 + i) * 512],
                                                 16, 0, 0);
            }
            const unsigned short* A1 = (c1 < 2) ? xinh : nh;   // steps 0-3: xh, 4-7: nh
            #pragma unroll
            for (int j = 0; j < 2; ++j)
                #pragma unroll
                for (int mt = 0; mt < 2; ++mt)
                    aN[j][mt] = *(const bf16x8*)&A1[abase[mt] + ((c1 & 1) * 2 + j) * 32];
        }
        #pragma unroll
        for (int j = 0; j < 2; ++j) {
            bf16x8 bf[4];
            #pragma unroll
            for (int nt = 0; nt < 4; ++nt)
                bf[nt] = *(const bf16x8*)&bbuf[c & 1][(j * 8 + nw * 4 + nt) * 512 + lane * 8];
            #pragma unroll
            for (int mt = 0; mt < 2; ++mt)
                #pragma unroll
                for (int nt = 0; nt < 4; ++nt)
                    acc[mt][nt] = __builtin_amdgcn_mfma_f32_16x16x32_bf16(aC[j][mt], bf[nt], acc[mt][nt], 0, 0, 0);
        }
        #pragma unroll
        for (int j = 0; j < 2; ++j)
            #pragma unroll
            for (int mt = 0; mt < 2; ++mt)
                aC[j][mt] = aN[j][mt];
    }

    // bias + relu (C/D: row = quad*4 + r, col = lane&15; h = (nw*4+nt)*16 + col)
    float sbv[4], nbv[4], gv[4], bbv[4];
    #pragma unroll
    for (int nt = 0; nt < 4; ++nt) {
        const int hh = (nw * 4 + nt) * 16 + col;
        sbv[nt] = sb[hh]; nbv[nt] = nb[hh]; gv[nt] = lng[hh]; bbv[nt] = lnb[hh];
    }
    #pragma unroll
    for (int mt = 0; mt < 2; ++mt)
        #pragma unroll
        for (int nt = 0; nt < 4; ++nt)
            #pragma unroll
            for (int r = 0; r < 4; ++r)
                acc[mt][nt][r] = fmaxf(acc[mt][nt][r] + sbv[nt] + nbv[nt], 0.f);

    // LN partials
    #pragma unroll
    for (int mt = 0; mt < 2; ++mt)
        #pragma unroll
        for (int r = 0; r < 4; ++r) {
            float p = 0.f, q = 0.f;
            #pragma unroll
            for (int nt = 0; nt < 4; ++nt) {
                const float v = acc[mt][nt][r];
                p += v;
                q = fmaf(v, v, q);
            }
            p += __shfl_xor(p, 1);  q += __shfl_xor(q, 1);
            p += __shfl_xor(p, 2);  q += __shfl_xor(q, 2);
            p += __shfl_xor(p, 4);  q += __shfl_xor(q, 4);
            p += __shfl_xor(p, 8);  q += __shfl_xor(q, 8);
            if (col == 0) {
                const int rib = (mg * 2 + mt) * 16 + quad * 4 + r;
                lsum[nw][rib] = p;
                lsq[nw][rib] = q;
            }
        }
    __syncthreads();   // all A-reads done before in-place stores

    float psum[4] = {0.f, 0.f, 0.f, 0.f};
    float pmax[4] = {-INFINITY, -INFINITY, -INFINITY, -INFINITY};

    #pragma unroll
    for (int mt = 0; mt < 2; ++mt)
        #pragma unroll
        for (int r = 0; r < 4; ++r) {
            const int rib = (mg * 2 + mt) * 16 + quad * 4 + r;
            const int node = row0 + rib;
            const float mu = (lsum[0][rib] + lsum[1][rib]) * (1.f / H);
            const float var = (lsq[0][rib] + lsq[1][rib]) * (1.f / H) - mu * mu;
            const float isd = rsqrtf(var + EPS);
            const float m = nmask[node];
            #pragma unroll
            for (int nt = 0; nt < 4; ++nt) {
                const float y = (fmaf(acc[mt][nt][r] - mu, isd * gv[nt], bbv[nt])) * m;
                if (!last) {
                    oxh[(size_t)node * H + (nw * 4 + nt) * 16 + col] = f2b(y);
                } else {
                    psum[nt] += y;
                    pmax[nt] = fmaxf(pmax[nt], (m > 0.f) ? y : -INFINITY);
                }
            }
        }

    if (!last) return;

    // pool partials for this block's 64 rows
    #pragma unroll
    for (int nt = 0; nt < 4; ++nt) {
        psum[nt] += __shfl_xor(psum[nt], 16);
        psum[nt] += __shfl_xor(psum[nt], 32);
        pmax[nt] = fmaxf(pmax[nt], __shfl_xor(pmax[nt], 16));
        pmax[nt] = fmaxf(pmax[nt], __shfl_xor(pmax[nt], 32));
    }
    if (quad == 0)
        #pragma unroll
        for (int nt = 0; nt < 4; ++nt) {
            psum_s[mg][(nw * 4 + nt) * 16 + col] = psum[nt];
            pmax_s[mg][(nw * 4 + nt) * 16 + col] = pmax[nt];
        }
    float nv = 0.f;
    if (wv == 0) {
        nv = nmask[row0 + lane];
        nv += __shfl_xor(nv, 1);  nv += __shfl_xor(nv, 2);
        nv += __shfl_xor(nv, 4);  nv += __shfl_xor(nv, 8);
        nv += __shfl_xor(nv, 16); nv += __shfl_xor(nv, 32);
    }
    __syncthreads();
    {
        float* p = part + ((size_t)b * NCHUNK + chunk) * (2 * H + 1);
        if (tid < H) {
            p[tid] = psum_s[0][tid] + psum_s[1][tid];
            p[H + tid] = fmaxf(pmax_s[0][tid], pmax_s[1][tid]);
        }
        if (tid == 0) p[2 * H] = nv;
    }

    // ---- last-block-done tail: final 8 tickets run the per-batch pool reduce + MLP head ----
    __threadfence();                              // release: part writes visible device-wide
    if (tid == 0) tick_s = atomicAdd(ctr, 1);
    __syncthreads();
    const int tick = tick_s;
    if (tick < LGRID - 8) return;
    if (tid == 0) {
        while (atomicAdd(ctr, 0) < LGRID) { __builtin_amdgcn_s_sleep(8); }
    }
    __syncthreads();
    __threadfence();                              // acquire
    const int bb = tick - (LGRID - 8);            // unique batch 0..7

    float accv = (tid < H) ? 0.f : -INFINITY;
    for (int c = 0; c < NCHUNK; ++c) {
        const float v = part[((size_t)bb * NCHUNK + c) * (2 * H + 1) + tid];
        accv = (tid < H) ? (accv + v) : fmaxf(accv, v);
    }
    if (tid < NCHUNK)
        nvl[tid] = part[((size_t)bb * NCHUNK + tid) * (2 * H + 1) + 2 * H];
    __syncthreads();
    for (int s = NCHUNK / 2; s > 0; s >>= 1) {
        if (tid < s) nvl[tid] += nvl[tid + s];
        __syncthreads();
    }
    const float nv2 = fmaxf(nvl[0], 1.f);
    float* g = &psum_s[0][0];                     // 256 floats (psum_s[2][H])
    float* hid = &pmax_s[0][0];                   // 128 floats
    g[tid] = (tid < H) ? accv / nv2 : accv;
    __syncthreads();
    if (tid < H) {
        float a = b1[tid];
        #pragma unroll 8
        for (int k = 0; k < 2 * H; ++k) a = fmaf(g[k], W1[k * H + tid], a);
        hid[tid] = fmaxf(a, 0.f);
    }
    __syncthreads();
    float a = b2[tid];
    #pragma unroll 8
    for (int k = 0; k < H; ++k) a = fmaf(hid[k], W2[k * OUTD + tid], a);
    out[(size_t)bb * OUTD + tid] = a;
}

extern "C" void kernel_launch(void* const* d_in, const int* in_sizes, int n_in,
                              void* d_out, int out_size, void* d_ws, size_t ws_size,
                              hipStream_t stream) {
    const float* feats = (const float*)d_in[0];
    const int*   ei    = (const int*)d_in[1];
    const float* nmask = (const float*)d_in[2];
    const float* emask = (const float*)d_in[3];
    const float* inW   = (const float*)d_in[4];
    const float* inb   = (const float*)d_in[5];
    const float* selfW = (const float*)d_in[6];
    const float* selfb = (const float*)d_in[7];
    const float* neighW= (const float*)d_in[8];
    const float* neighb= (const float*)d_in[9];
    const float* lng   = (const float*)d_in[10];
    const float* lnb   = (const float*)d_in[11];
    const float* W1    = (const float*)d_in[12];
    const float* b1    = (const float*)d_in[13];
    const float* W2    = (const float*)d_in[14];
    const float* b2    = (const float*)d_in[15];
    float* out = (float*)d_out;

    const size_t nxh = (size_t)NNODE * H;
    char* w = (char*)d_ws;
    unsigned short* xh  = (unsigned short*)w;  w += nxh * 2;
    unsigned short* nh  = (unsigned short*)w;  w += nxh * 2;
    unsigned short* Bp  = (unsigned short*)w;  w += (size_t)NLAYER * BPL * 2;
    unsigned short* Bpi = (unsigned short*)w;  w += (size_t)INSTEPS * 8 * 512 * 2;
    float* part = (float*)w;                   w += (size_t)B * NCHUNK * (2 * H + 1) * 4;
    int* ecnt   = (int*)w;                     w += (size_t)NNODE * 4;
    int* ctr    = (int*)w;                     w += 16;
    unsigned int* ell = (unsigned int*)w;      w += (size_t)NNODE * ELLW * 4;

    // node 1: prep (weights) + zero ecnt/ctr
    k_prep<<<PREPN + NNODE / 64, 64, 0, stream>>>(selfW, neighW, inW, Bp, Bpi, ecnt, ctr);
    // node 2: inproj || ELL fill
    k_front<<<1024 + B * E / 256, 256, 0, stream>>>(feats, Bpi, inb, xh, ei, emask, ecnt, ell);

    // nodes 3-8: 3 x (gather, layer); last layer runs the fused tail via ticket pattern
    for (int l = 0; l < NLAYER; ++l) {
        k_gather7<<<NNODE / 4, 256, 0, stream>>>((const unsigned int*)xh, ecnt, ell,
                                                 (unsigned int*)nh);
        k_layer10<<<LGRID, 256, 0, stream>>>(xh, nh,
                                             Bp + (size_t)l * BPL,
                                             selfb + (size_t)l * H, neighb + (size_t)l * H,
                                             lng + (size_t)l * H, lnb + (size_t)l * H,
                                             nmask, xh, part,
                                             W1, b1, W2, b2, out, ctr,
                                             (l == NLAYER - 1) ? 1 : 0);
    }
}

// Round 16
// 250.889 us; speedup vs baseline: 3.6136x; 1.3474x over previous
//
#include <hip/hip_runtime.h>
#include <hip/hip_bf16.h>

#define B 8
#define N 8192
#define E 65536
#define FIN 64
#define H 128
#define OUTD 256
#define NLAYER 3
#define EPS 1e-5f
#define NCHUNK 128               // pool chunks per batch (one per 64-row layer block)
#define NNODE (B * N)            // 65536 rows
#define KSTEPS 8                 // 2 groups x 4 k-steps of K=32 (xh*sWhi, nh*nWhi)
#define BPL (KSTEPS * 8 * 512)   // Bp ushort elems per layer
#define INSTEPS 6                // inproj: 3 groups x 2 k-steps (fh*Whi, fl*Whi, fh*Wlo)
#define ELLW 48                  // max incoming edges/node (Poisson(8): P(>48) ~ 1e-25)
#define PREPN (NLAYER * KSTEPS * 8 + INSTEPS * 8)   // 240 prep blocks

#define AS1 __attribute__((address_space(1)))
#define AS3 __attribute__((address_space(3)))

typedef float f32x4 __attribute__((ext_vector_type(4)));
typedef __bf16 bf16x8 __attribute__((ext_vector_type(8)));

__device__ __forceinline__ float b2f(unsigned short u) {
    union { float f; unsigned int i; } c; c.i = ((unsigned int)u) << 16; return c.f;
}
__device__ __forceinline__ unsigned short f2b(float f) {
    __hip_bfloat16 h = __float2bfloat16(f);          // RTNE
    return *reinterpret_cast<unsigned short*>(&h);
}

// ---------------- weight pre-pack + ecnt zeroing (one node) ----------------
__global__ void k_prep(const float* __restrict__ selfW, const float* __restrict__ neighW,
                       const float* __restrict__ inW,
                       unsigned short* __restrict__ Bp, unsigned short* __restrict__ Bpi,
                       int* __restrict__ ecnt) {
    const int idx = blockIdx.x;
    const int lane = threadIdx.x;
    const int quad = lane >> 4, col = lane & 15;
    if (idx >= PREPN) {
        ecnt[(idx - PREPN) * 64 + lane] = 0;
        return;
    }
    if (idx < NLAYER * KSTEPS * 8) {
        const int t = idx & 7;
        const int s = (idx >> 3) % KSTEPS;
        const int l = idx / (KSTEPS * 8);
        const float* W = (((s >> 2) == 0) ? selfW : neighW) + (size_t)l * H * H;
        const int n = t * 16 + col;
        unsigned short* dst = Bp + ((size_t)(l * KSTEPS + s) * 8 + t) * 512 + lane * 8;
        #pragma unroll
        for (int j = 0; j < 8; ++j)
            dst[j] = f2b(W[((s & 3) * 32 + quad * 8 + j) * H + n]);
    } else {
        const int idx2 = idx - NLAYER * KSTEPS * 8;
        const int t = idx2 & 7;
        const int s = idx2 >> 3;                     // 0..5
        const bool lo = ((s >> 1) == 2);
        const int n = t * 16 + col;
        unsigned short* dst = Bpi + ((size_t)(s * 8 + t)) * 512 + lane * 8;
        #pragma unroll
        for (int j = 0; j < 8; ++j) {
            const float w = inW[((s & 1) * 32 + quad * 8 + j) * H + n];
            const unsigned short hi = f2b(w);
            dst[j] = lo ? f2b(w - b2f(hi)) : hi;
        }
    }
}

// ---------------- fat kernel: inproj (blocks 0..1023) || ELL fill (blocks 1024..3071) ----------------
__global__ __launch_bounds__(256) void k_front(const float* __restrict__ feats,
                                               const unsigned short* __restrict__ Bpi,
                                               const float* __restrict__ bias,
                                               unsigned short* __restrict__ xh,
                                               const int* __restrict__ ei,
                                               const float* __restrict__ emask,
                                               int* __restrict__ ecnt,
                                               unsigned int* __restrict__ ell) {
    const int tid = threadIdx.x;
    if (blockIdx.x >= 1024) {
        const int ge = (blockIdx.x - 1024) * 256 + tid;      // b*E + e
        const float m = emask[ge];
        if (m > 0.f) {
            const int b = ge >> 16, e = ge & 0xFFFF;
            const int tgt = ei[(b * 2 + 1) * E + e];
            const int src = ei[(b * 2) * E + e];
            const int r = b * N + tgt;
            const int p = atomicAdd(&ecnt[r], 1);
            if (p < ELLW)
                ell[(size_t)r * ELLW + p] = ((unsigned int)f2b(m) << 16) | (unsigned int)src;
        }
        return;
    }
    const int wv = tid >> 6, lane = tid & 63;
    const int quad = lane >> 4, col = lane & 15;
    const int mg = wv >> 1, nw = wv & 1;
    const int row0 = blockIdx.x * 64;
    bf16x8 fh[2][2], fl[2][2];
    #pragma unroll
    for (int mt = 0; mt < 2; ++mt) {
        const int row = row0 + (mg * 2 + mt) * 16 + col;
        #pragma unroll
        for (int j = 0; j < 2; ++j) {
            const float* src = &feats[(size_t)row * FIN + j * 32 + quad * 8];
            const float4 v0 = *(const float4*)src;
            const float4 v1 = *(const float4*)(src + 4);
            const float fv[8] = {v0.x, v0.y, v0.z, v0.w, v1.x, v1.y, v1.z, v1.w};
            union { bf16x8 v; unsigned short u[8]; } Hh, Ll;
            #pragma unroll
            for (int q = 0; q < 8; ++q) {
                const unsigned short hu = f2b(fv[q]);
                Hh.u[q] = hu;
                Ll.u[q] = f2b(fv[q] - b2f(hu));
            }
            fh[mt][j] = Hh.v;
            fl[mt][j] = Ll.v;
        }
    }
    f32x4 acc[2][4] = {};
    bf16x8 bC[4];
    #pragma unroll
    for (int nt = 0; nt < 4; ++nt)
        bC[nt] = *(const bf16x8*)&Bpi[((size_t)(nw * 4 + nt)) * 512 + lane * 8];
    #pragma unroll
    for (int s = 0; s < INSTEPS; ++s) {
        bf16x8 bN[4];
        if (s + 1 < INSTEPS) {
            #pragma unroll
            for (int nt = 0; nt < 4; ++nt)
                bN[nt] = *(const bf16x8*)&Bpi[((size_t)(s + 1) * 8 + nw * 4 + nt) * 512 + lane * 8];
        }
        const int g = s >> 1, j = s & 1;
        #pragma unroll
        for (int mt = 0; mt < 2; ++mt) {
            const bf16x8 a = (g == 1) ? fl[mt][j] : fh[mt][j];
            #pragma unroll
            for (int nt = 0; nt < 4; ++nt)
                acc[mt][nt] = __builtin_amdgcn_mfma_f32_16x16x32_bf16(a, bC[nt], acc[mt][nt], 0, 0, 0);
        }
        #pragma unroll
        for (int nt = 0; nt < 4; ++nt) bC[nt] = bN[nt];
    }
    #pragma unroll
    for (int nt = 0; nt < 4; ++nt) {
        const int hh = (nw * 4 + nt) * 16 + col;
        const float bv = bias[hh];
        #pragma unroll
        for (int mt = 0; mt < 2; ++mt)
            #pragma unroll
            for (int r = 0; r < 4; ++r) {
                const int row = row0 + (mg * 2 + mt) * 16 + quad * 4 + r;
                xh[(size_t)row * H + hh] = f2b(fmaxf(acc[mt][nt][r] + bv, 0.f));
            }
    }
}

// ---------------- gather: speculative ELL read, unroll-8, one wave per row ----------------
__global__ __launch_bounds__(256) void k_gather7(const unsigned int* __restrict__ xh32,
                                                 const int* __restrict__ ecnt,
                                                 const unsigned int* __restrict__ ell,
                                                 unsigned int* __restrict__ nh32) {
    const int beta = blockIdx.x;               // 0..16383
    const int b = beta & 7;
    const int grp = beta >> 3;
    const int wave = threadIdx.x >> 6, lane = threadIdx.x & 63;
    const int r = b * N + grp * 4 + wave;
    unsigned int pv = 0;
    if (lane < ELLW) pv = ell[(size_t)r * ELLW + lane];
    const int cnt = min(ecnt[r], ELLW);
    if (lane >= cnt) pv = 0;
    const size_t bbase = (size_t)b * N * 64;
    float a0 = 0.f, a1 = 0.f, c = 0.f;
    const int cnt8 = (cnt + 7) & ~7;
    for (int jj = 0; jj < cnt8; jj += 8) {
        #pragma unroll
        for (int q = 0; q < 8; ++q) {
            const unsigned int pk = __shfl(pv, jj + q);
            const float m = b2f((unsigned short)(pk >> 16));
            const unsigned int u = xh32[bbase + (size_t)(pk & 0xFFFFu) * 64 + lane];
            union { unsigned int i; float f; } lo, hi;
            lo.i = u << 16;
            hi.i = u & 0xFFFF0000u;
            a0 = fmaf(lo.f, m, a0);
            a1 = fmaf(hi.f, m, a1);
            c += m;
        }
    }
    const float inv = 1.f / fmaxf(c, 1.f);
    nh32[(size_t)r * 64 + lane] = (unsigned int)f2b(a0 * inv) | ((unsigned int)f2b(a1 * inv) << 16);
}

// ---------------- fused layer: LDS-staged B; last layer emits pool partials ----------------
__global__ __launch_bounds__(256) void k_layer9(const unsigned short* __restrict__ xinh,
                                                const unsigned short* __restrict__ nh,
                                                const unsigned short* __restrict__ Bp,
                                                const float* __restrict__ sb,
                                                const float* __restrict__ nb,
                                                const float* __restrict__ lng,
                                                const float* __restrict__ lnb,
                                                const float* __restrict__ nmask,
                                                unsigned short* __restrict__ oxh,
                                                float* __restrict__ part,
                                                const int last) {
    __shared__ __align__(16) unsigned short bbuf[2][16 * 512];   // 2 x 16 KB
    __shared__ float lsum[2][64];
    __shared__ float lsq[2][64];
    __shared__ float psum_s[2][H];
    __shared__ float pmax_s[2][H];
    const int tid = threadIdx.x;
    const int wv = tid >> 6, lane = tid & 63;
    const int quad = lane >> 4, col = lane & 15;
    const int mg = wv >> 1, nw = wv & 1;
    const int u = blockIdx.x;
    const int b = u & 7;
    const int chunk = u >> 3;                     // 0..127
    const int row0 = b * N + chunk * 64;          // batch-pinned to XCD b
    size_t abase[2];
    #pragma unroll
    for (int mt = 0; mt < 2; ++mt)
        abase[mt] = (size_t)(row0 + (mg * 2 + mt) * 16 + col) * H + quad * 8;
    #pragma unroll
    for (int i = 0; i < 4; ++i) {
        const unsigned short* g = Bp + (size_t)(wv * 4 + i) * 512 + lane * 8;
        __builtin_amdgcn_global_load_lds((const AS1 unsigned int*)g,
                                         (AS3 unsigned int*)&bbuf[0][(wv * 4 + i) * 512],
                                         16, 0, 0);
    }
    bf16x8 aC[2][2];
    #pragma unroll
    for (int j = 0; j < 2; ++j)
        #pragma unroll
        for (int mt = 0; mt < 2; ++mt)
            aC[j][mt] = *(const bf16x8*)&xinh[abase[mt] + j * 32];
    f32x4 acc[2][4] = {};
    #pragma unroll
    for (int c = 0; c < 4; ++c) {
        __syncthreads();
        bf16x8 aN[2][2];
        if (c < 3) {
            const int c1 = c + 1;
            #pragma unroll
            for (int i = 0; i < 4; ++i) {
                const unsigned short* g = Bp + (size_t)(c1 * 16 + wv * 4 + i) * 512 + lane * 8;
                __builtin_amdgcn_global_load_lds((const AS1 unsigned int*)g,
                                                 (AS3 unsigned int*)&bbuf[c1 & 1][(wv * 4 + i) * 512],
                                                 16, 0, 0);
            }
            const unsigned short* A1 = (c1 < 2) ? xinh : nh;   // steps 0-3: xh, 4-7: nh
            #pragma unroll
            for (int j = 0; j < 2; ++j)
                #pragma unroll
                for (int mt = 0; mt < 2; ++mt)
                    aN[j][mt] = *(const bf16x8*)&A1[abase[mt] + ((c1 & 1) * 2 + j) * 32];
        }
        #pragma unroll
        for (int j = 0; j < 2; ++j) {
            bf16x8 bf[4];
            #pragma unroll
            for (int nt = 0; nt < 4; ++nt)
                bf[nt] = *(const bf16x8*)&bbuf[c & 1][(j * 8 + nw * 4 + nt) * 512 + lane * 8];
            #pragma unroll
            for (int mt = 0; mt < 2; ++mt)
                #pragma unroll
                for (int nt = 0; nt < 4; ++nt)
                    acc[mt][nt] = __builtin_amdgcn_mfma_f32_16x16x32_bf16(aC[j][mt], bf[nt], acc[mt][nt], 0, 0, 0);
        }
        #pragma unroll
        for (int j = 0; j < 2; ++j)
            #pragma unroll
            for (int mt = 0; mt < 2; ++mt)
                aC[j][mt] = aN[j][mt];
    }
    float sbv[4], nbv[4], gv[4], bbv[4];
    #pragma unroll
    for (int nt = 0; nt < 4; ++nt) {
        const int hh = (nw * 4 + nt) * 16 + col;
        sbv[nt] = sb[hh]; nbv[nt] = nb[hh]; gv[nt] = lng[hh]; bbv[nt] = lnb[hh];
    }
    #pragma unroll
    for (int mt = 0; mt < 2; ++mt)
        #pragma unroll
        for (int nt = 0; nt < 4; ++nt)
            #pragma unroll
            for (int r = 0; r < 4; ++r)
                acc[mt][nt][r] = fmaxf(acc[mt][nt][r] + sbv[nt] + nbv[nt], 0.f);
    #pragma unroll
    for (int mt = 0; mt < 2; ++mt)
        #pragma unroll
        for (int r = 0; r < 4; ++r) {
            float p = 0.f, q = 0.f;
            #pragma unroll
            for (int nt = 0; nt < 4; ++nt) {
                const float v = acc[mt][nt][r];
                p += v;
                q = fmaf(v, v, q);
            }
            p += __shfl_xor(p, 1);  q += __shfl_xor(q, 1);
            p += __shfl_xor(p, 2);  q += __shfl_xor(q, 2);
            p += __shfl_xor(p, 4);  q += __shfl_xor(q, 4);
            p += __shfl_xor(p, 8);  q += __shfl_xor(q, 8);
            if (col == 0) {
                const int rib = (mg * 2 + mt) * 16 + quad * 4 + r;
                lsum[nw][rib] = p;
                lsq[nw][rib] = q;
            }
        }
    __syncthreads();   // all A-reads done before in-place stores
    float psum[4] = {0.f, 0.f, 0.f, 0.f};
    float pmax[4] = {-INFINITY, -INFINITY, -INFINITY, -INFINITY};
    #pragma unroll
    for (int mt = 0; mt < 2; ++mt)
        #pragma unroll
        for (int r = 0; r < 4; ++r) {
            const int rib = (mg * 2 + mt) * 16 + quad * 4 + r;
            const int node = row0 + rib;
            const float mu = (lsum[0][rib] + lsum[1][rib]) * (1.f / H);
            const float var = (lsq[0][rib] + lsq[1][rib]) * (1.f / H) - mu * mu;
            const float isd = rsqrtf(var + EPS);
            const float m = nmask[node];
            #pragma unroll
            for (int nt = 0; nt < 4; ++nt) {
                const float y = (fmaf(acc[mt][nt][r] - mu, isd * gv[nt], bbv[nt])) * m;
                if (!last) {
                    oxh[(size_t)node * H + (nw * 4 + nt) * 16 + col] = f2b(y);
                } else {
                    psum[nt] += y;
                    pmax[nt] = fmaxf(pmax[nt], (m > 0.f) ? y : -INFINITY);
                }
            }
        }
    if (!last) return;
    #pragma unroll
    for (int nt = 0; nt < 4; ++nt) {
        psum[nt] += __shfl_xor(psum[nt], 16);
        psum[nt] += __shfl_xor(psum[nt], 32);
        pmax[nt] = fmaxf(pmax[nt], __shfl_xor(pmax[nt], 16));
        pmax[nt] = fmaxf(pmax[nt], __shfl_xor(pmax[nt], 32));
    }
    if (quad == 0)
        #pragma unroll
        for (int nt = 0; nt < 4; ++nt) {
            psum_s[mg][(nw * 4 + nt) * 16 + col] = psum[nt];
            pmax_s[mg][(nw * 4 + nt) * 16 + col] = pmax[nt];
        }
    float nv = 0.f;
    if (wv == 0) {
        nv = nmask[row0 + lane];
        nv += __shfl_xor(nv, 1);  nv += __shfl_xor(nv, 2);
        nv += __shfl_xor(nv, 4);  nv += __shfl_xor(nv, 8);
        nv += __shfl_xor(nv, 16); nv += __shfl_xor(nv, 32);
    }
    __syncthreads();
    float* p = part + ((size_t)b * NCHUNK + chunk) * (2 * H + 1);
    if (tid < H) {
        p[tid] = psum_s[0][tid] + psum_s[1][tid];
        p[H + tid] = fmaxf(pmax_s[0][tid], pmax_s[1][tid]);
    }
    if (tid == 0) p[2 * H] = nv;
}

// ---------------- fused pool-reduce + MLP head (1024 threads, 4-way chunk split) ----------------
__global__ __launch_bounds__(1024) void k_tail2(const float* __restrict__ part,
                                                const float* __restrict__ W1, const float* __restrict__ b1,
                                                const float* __restrict__ W2, const float* __restrict__ b2,
                                                float* __restrict__ out) {
    const int b = blockIdx.x, tid = threadIdx.x;
    const int col = tid & 255;
    const int sub = tid >> 8;
    __shared__ float sred[4][2 * H];
    __shared__ float nvl[NCHUNK];
    __shared__ float g[2 * H];
    __shared__ float hid[H];
    {
        float acc = (col < H) ? 0.f : -INFINITY;
        #pragma unroll 8
        for (int c = sub * (NCHUNK / 4); c < (sub + 1) * (NCHUNK / 4); ++c) {
            const float v = part[((size_t)b * NCHUNK + c) * (2 * H + 1) + col];
            acc = (col < H) ? (acc + v) : fmaxf(acc, v);
        }
        sred[sub][col] = acc;
    }
    if (tid < NCHUNK)
        nvl[tid] = part[((size_t)b * NCHUNK + tid) * (2 * H + 1) + 2 * H];
    __syncthreads();
    for (int s = NCHUNK / 2; s > 0; s >>= 1) {
        if (tid < s) nvl[tid] += nvl[tid + s];
        __syncthreads();
    }
    const float nv = fmaxf(nvl[0], 1.f);
    if (tid < 2 * H) {
        if (tid < H)
            g[tid] = (sred[0][tid] + sred[1][tid] + sred[2][tid] + sred[3][tid]) / nv;
        else
            g[tid] = fmaxf(fmaxf(sred[0][tid], sred[1][tid]), fmaxf(sred[2][tid], sred[3][tid]));
    }
    __syncthreads();
    if (tid < H) {
        float a = b1[tid];
        #pragma unroll 8
        for (int k = 0; k < 2 * H; ++k) a = fmaf(g[k], W1[k * H + tid], a);
        hid[tid] = fmaxf(a, 0.f);
    }
    __syncthreads();
    if (tid < OUTD) {
        float a = b2[tid];
        #pragma unroll 8
        for (int k = 0; k < H; ++k) a = fmaf(hid[k], W2[k * OUTD + tid], a);
        out[(size_t)b * OUTD + tid] = a;
    }
}

extern "C" void kernel_launch(void* const* d_in, const int* in_sizes, int n_in,
                              void* d_out, int out_size, void* d_ws, size_t ws_size,
                              hipStream_t stream) {
    const float* feats = (const float*)d_in[0];
    const int*   ei    = (const int*)d_in[1];
    const float* nmask = (const float*)d_in[2];
    const float* emask = (const float*)d_in[3];
    const float* inW   = (const float*)d_in[4];
    const float* inb   = (const float*)d_in[5];
    const float* selfW = (const float*)d_in[6];
    const float* selfb = (const float*)d_in[7];
    const float* neighW= (const float*)d_in[8];
    const float* neighb= (const float*)d_in[9];
    const float* lng   = (const float*)d_in[10];
    const float* lnb   = (const float*)d_in[11];
    const float* W1    = (const float*)d_in[12];
    const float* b1    = (const float*)d_in[13];
    const float* W2    = (const float*)d_in[14];
    const float* b2    = (const float*)d_in[15];
    float* out = (float*)d_out;

    const size_t nxh = (size_t)NNODE * H;
    char* w = (char*)d_ws;
    unsigned short* xh  = (unsigned short*)w;  w += nxh * 2;
    unsigned short* nh  = (unsigned short*)w;  w += nxh * 2;
    unsigned short* Bp  = (unsigned short*)w;  w += (size_t)NLAYER * BPL * 2;
    unsigned short* Bpi = (unsigned short*)w;  w += (size_t)INSTEPS * 8 * 512 * 2;
    float* part = (float*)w;                   w += (size_t)B * NCHUNK * (2 * H + 1) * 4;
    int* ecnt   = (int*)w;                     w += (size_t)NNODE * 4;
    unsigned int* ell = (unsigned int*)w;      w += (size_t)NNODE * ELLW * 4;

    // node 1: prep (weights) + zero ecnt
    k_prep<<<PREPN + NNODE / 64, 64, 0, stream>>>(selfW, neighW, inW, Bp, Bpi, ecnt);
    // node 2: inproj || ELL fill
    k_front<<<1024 + B * E / 256, 256, 0, stream>>>(feats, Bpi, inb, xh, ei, emask, ecnt, ell);
    // nodes 3-8: 3 x (gather, layer); last layer emits pool partials
    for (int l = 0; l < NLAYER; ++l) {
        k_gather7<<<NNODE / 4, 256, 0, stream>>>((const unsigned int*)xh, ecnt, ell,
                                                 (unsigned int*)nh);
        k_layer9<<<NNODE / 64, 256, 0, stream>>>(xh, nh,
                                                 Bp + (size_t)l * BPL,
                                                 selfb + (size_t)l * H, neighb + (size_t)l * H,
                                                 lng + (size_t)l * H, lnb + (size_t)l * H,
                                                 nmask, xh, part, (l == NLAYER - 1) ? 1 : 0);
    }
    // node 9: pool-reduce + MLP head
    k_tail2<<<B, 1024, 0, stream>>>(part, W1, b1, W2, b2, out);
}

// Round 17
// 246.135 us; speedup vs baseline: 3.6834x; 1.0193x over previous
//
#include <hip/hip_runtime.h>
#include <hip/hip_bf16.h>

#define B 8
#define N 8192
#define E 65536
#define FIN 64
#define H 128
#define OUTD 256
#define NLAYER 3
#define EPS 1e-5f
#define NCHUNK 128               // pool chunks per batch (one per 64-row fused block)
#define NNODE (B * N)            // 65536 rows
#define KSTEPS 8                 // 2 groups x 4 k-steps of K=32 (xh*sWhi, nh*nWhi)
#define BPL (KSTEPS * 8 * 512)   // Bp ushort elems per layer
#define INSTEPS 6                // inproj: 3 groups x 2 k-steps (fh*Whi, fl*Whi, fh*Wlo)
#define ELLW 32                  // max incoming edges/node (Poisson(8): P(>32) ~ 2e-11)
#define PREPN (NLAYER * KSTEPS * 8 + INSTEPS * 8)   // 240 prep blocks

#define AS1 __attribute__((address_space(1)))
#define AS3 __attribute__((address_space(3)))

typedef float f32x4 __attribute__((ext_vector_type(4)));
typedef __bf16 bf16x8 __attribute__((ext_vector_type(8)));

__device__ __forceinline__ float b2f(unsigned short u) {
    union { float f; unsigned int i; } c; c.i = ((unsigned int)u) << 16; return c.f;
}
__device__ __forceinline__ unsigned short f2b(float f) {
    __hip_bfloat16 h = __float2bfloat16(f);          // RTNE
    return *reinterpret_cast<unsigned short*>(&h);
}

// ---------------- weight pre-pack + ecnt zeroing (one node) ----------------
__global__ void k_prep(const float* __restrict__ selfW, const float* __restrict__ neighW,
                       const float* __restrict__ inW,
                       unsigned short* __restrict__ Bp, unsigned short* __restrict__ Bpi,
                       int* __restrict__ ecnt) {
    const int idx = blockIdx.x;
    const int lane = threadIdx.x;
    const int quad = lane >> 4, col = lane & 15;
    if (idx >= PREPN) {
        ecnt[(idx - PREPN) * 64 + lane] = 0;
        return;
    }
    if (idx < NLAYER * KSTEPS * 8) {
        const int t = idx & 7;
        const int s = (idx >> 3) % KSTEPS;
        const int l = idx / (KSTEPS * 8);
        const float* W = (((s >> 2) == 0) ? selfW : neighW) + (size_t)l * H * H;
        const int n = t * 16 + col;
        unsigned short* dst = Bp + ((size_t)(l * KSTEPS + s) * 8 + t) * 512 + lane * 8;
        #pragma unroll
        for (int j = 0; j < 8; ++j)
            dst[j] = f2b(W[((s & 3) * 32 + quad * 8 + j) * H + n]);
    } else {
        const int idx2 = idx - NLAYER * KSTEPS * 8;
        const int t = idx2 & 7;
        const int s = idx2 >> 3;                     // 0..5
        const bool lo = ((s >> 1) == 2);
        const int n = t * 16 + col;
        unsigned short* dst = Bpi + ((size_t)(s * 8 + t)) * 512 + lane * 8;
        #pragma unroll
        for (int j = 0; j < 8; ++j) {
            const float w = inW[((s & 1) * 32 + quad * 8 + j) * H + n];
            const unsigned short hi = f2b(w);
            dst[j] = lo ? f2b(w - b2f(hi)) : hi;
        }
    }
}

// ---------------- fat kernel: inproj (blocks 0..1023) || ELL fill (blocks 1024..3071) ----------------
__global__ __launch_bounds__(256) void k_front(const float* __restrict__ feats,
                                               const unsigned short* __restrict__ Bpi,
                                               const float* __restrict__ bias,
                                               unsigned short* __restrict__ xh,
                                               const int* __restrict__ ei,
                                               const float* __restrict__ emask,
                                               int* __restrict__ ecnt,
                                               unsigned int* __restrict__ ell) {
    const int tid = threadIdx.x;
    if (blockIdx.x >= 1024) {
        const int ge = (blockIdx.x - 1024) * 256 + tid;      // b*E + e
        const float m = emask[ge];
        if (m > 0.f) {
            const int b = ge >> 16, e = ge & 0xFFFF;
            const int tgt = ei[(b * 2 + 1) * E + e];
            const int src = ei[(b * 2) * E + e];
            const int r = b * N + tgt;
            const int p = atomicAdd(&ecnt[r], 1);
            if (p < ELLW)
                ell[(size_t)r * ELLW + p] = ((unsigned int)f2b(m) << 16) | (unsigned int)src;
        }
        return;
    }
    const int wv = tid >> 6, lane = tid & 63;
    const int quad = lane >> 4, col = lane & 15;
    const int mg = wv >> 1, nw = wv & 1;
    const int row0 = blockIdx.x * 64;
    bf16x8 fh[2][2], fl[2][2];
    #pragma unroll
    for (int mt = 0; mt < 2; ++mt) {
        const int row = row0 + (mg * 2 + mt) * 16 + col;
        #pragma unroll
        for (int j = 0; j < 2; ++j) {
            const float* src = &feats[(size_t)row * FIN + j * 32 + quad * 8];
            const float4 v0 = *(const float4*)src;
            const float4 v1 = *(const float4*)(src + 4);
            const float fv[8] = {v0.x, v0.y, v0.z, v0.w, v1.x, v1.y, v1.z, v1.w};
            union { bf16x8 v; unsigned short u[8]; } Hh, Ll;
            #pragma unroll
            for (int q = 0; q < 8; ++q) {
                const unsigned short hu = f2b(fv[q]);
                Hh.u[q] = hu;
                Ll.u[q] = f2b(fv[q] - b2f(hu));
            }
            fh[mt][j] = Hh.v;
            fl[mt][j] = Ll.v;
        }
    }
    f32x4 acc[2][4] = {};
    bf16x8 bC[4];
    #pragma unroll
    for (int nt = 0; nt < 4; ++nt)
        bC[nt] = *(const bf16x8*)&Bpi[((size_t)(nw * 4 + nt)) * 512 + lane * 8];
    #pragma unroll
    for (int s = 0; s < INSTEPS; ++s) {
        bf16x8 bN[4];
        if (s + 1 < INSTEPS) {
            #pragma unroll
            for (int nt = 0; nt < 4; ++nt)
                bN[nt] = *(const bf16x8*)&Bpi[((size_t)(s + 1) * 8 + nw * 4 + nt) * 512 + lane * 8];
        }
        const int g = s >> 1, j = s & 1;
        #pragma unroll
        for (int mt = 0; mt < 2; ++mt) {
            const bf16x8 a = (g == 1) ? fl[mt][j] : fh[mt][j];
            #pragma unroll
            for (int nt = 0; nt < 4; ++nt)
                acc[mt][nt] = __builtin_amdgcn_mfma_f32_16x16x32_bf16(a, bC[nt], acc[mt][nt], 0, 0, 0);
        }
        #pragma unroll
        for (int nt = 0; nt < 4; ++nt) bC[nt] = bN[nt];
    }
    #pragma unroll
    for (int nt = 0; nt < 4; ++nt) {
        const int hh = (nw * 4 + nt) * 16 + col;
        const float bv = bias[hh];
        #pragma unroll
        for (int mt = 0; mt < 2; ++mt)
            #pragma unroll
            for (int r = 0; r < 4; ++r) {
                const int row = row0 + (mg * 2 + mt) * 16 + quad * 4 + r;
                xh[(size_t)row * H + hh] = f2b(fmaxf(acc[mt][nt][r] + bv, 0.f));
            }
    }
}

// ---------------- fused gather+layer v2: 64 rows/block, 1024 blocks, full residency ----------------
// Phase A: wave wv gathers rows [wv*16, wv*16+16): ELL rows bulk-loaded to registers,
//          entries shfl-broadcast, unroll-8 loads; result -> nh_s (pitch 68 u32, 2-way banks = free).
// Phase B: MFMA layer; steps 0-3 A=xin (global, own rows), steps 4-7 A=nh_s (LDS);
//          B double-buffered 8 KB/step via global_load_lds. Out-of-place xin->xout.
__global__ __launch_bounds__(256, 4) void k_fused2(const unsigned short* __restrict__ xin,
                                                   unsigned short* __restrict__ xout,
                                                   const int* __restrict__ ecnt,
                                                   const unsigned int* __restrict__ ell,
                                                   const unsigned short* __restrict__ Bp,
                                                   const float* __restrict__ sb,
                                                   const float* __restrict__ nb,
                                                   const float* __restrict__ lng,
                                                   const float* __restrict__ lnb,
                                                   const float* __restrict__ nmask,
                                                   float* __restrict__ part,
                                                   const int last) {
    __shared__ __align__(16) unsigned short bbuf[2][8 * 512];    // 2 x 8 KB (1 k-step each)
    __shared__ __align__(16) unsigned int nh_s[64 * 68];         // 17.4 KB, pitch 68 u32
    __shared__ float lsum[2][64];
    __shared__ float lsq[2][64];
    __shared__ float psum_s[2][H];
    __shared__ float pmax_s[2][H];

    const int tid = threadIdx.x;
    const int wv = tid >> 6, lane = tid & 63;
    const int quad = lane >> 4, col = lane & 15;
    const int u = blockIdx.x;
    const int b = u & 7;
    const int chunk = u >> 3;                     // 0..127
    const int row0 = b * N + chunk * 64;          // batch-pinned to XCD b

    // ---- phase A: gather own 64 rows (wave wv -> local rows wv*16..+15) ----
    {
        const int r0w = row0 + wv * 16;
        int myc = 0;
        if (lane < 16) myc = min(ecnt[r0w + lane], ELLW);
        unsigned int er[8];                       // 16 rows x 32 entries; flat=k*64+lane
        const unsigned int* ebase = ell + (size_t)r0w * ELLW;
        #pragma unroll
        for (int k = 0; k < 8; ++k) er[k] = ebase[k * 64 + lane];
        const unsigned int* xin32 = (const unsigned int*)xin;
        const size_t bbase = (size_t)b * N * 64;
        #pragma unroll
        for (int rr = 0; rr < 16; ++rr) {
            const int cnt = __shfl(myc, rr);
            const int base = (rr & 1) * 32;
            float a0 = 0.f, a1 = 0.f, c = 0.f;
            const int cnt8 = (cnt + 7) & ~7;
            for (int jj = 0; jj < cnt8; jj += 8) {
                #pragma unroll
                for (int q = 0; q < 8; ++q) {
                    const int s = jj + q;
                    const unsigned int pk = __shfl(er[rr >> 1], base + s);
                    const float m = (s < cnt) ? b2f((unsigned short)(pk >> 16)) : 0.f;
                    const unsigned int uu = xin32[bbase + (size_t)(pk & (N - 1)) * 64 + lane];
                    union { unsigned int i; float f; } lo, hi;
                    lo.i = uu << 16;
                    hi.i = uu & 0xFFFF0000u;
                    a0 = fmaf(lo.f, m, a0);
                    a1 = fmaf(hi.f, m, a1);
                    c += m;
                }
            }
            const float inv = 1.f / fmaxf(c, 1.f);
            nh_s[(wv * 16 + rr) * 68 + lane] =
                (unsigned int)f2b(a0 * inv) | ((unsigned int)f2b(a1 * inv) << 16);
        }
    }

    // ---- phase B: MFMA layer ----
    const int mg = (tid >> 6) >> 1, nw = (tid >> 6) & 1;
    size_t abase[2];
    int rloc[2];
    #pragma unroll
    for (int mt = 0; mt < 2; ++mt) {
        rloc[mt] = (mg * 2 + mt) * 16 + col;
        abase[mt] = (size_t)(row0 + rloc[mt]) * H + quad * 8;
    }
    const unsigned short* nh16 = (const unsigned short*)nh_s;   // pitch 136 shorts

    // stage step 0 B (8 tiles; wave wv stages tiles wv*2, wv*2+1)
    #pragma unroll
    for (int i = 0; i < 2; ++i) {
        const unsigned short* g = Bp + (size_t)(wv * 2 + i) * 512 + lane * 8;
        __builtin_amdgcn_global_load_lds((const AS1 unsigned int*)g,
                                         (AS3 unsigned int*)&bbuf[0][(wv * 2 + i) * 512],
                                         16, 0, 0);
    }
    bf16x8 aC[2];
    #pragma unroll
    for (int mt = 0; mt < 2; ++mt)
        aC[mt] = *(const bf16x8*)&xin[abase[mt]];

    f32x4 acc[2][4] = {};

    #pragma unroll
    for (int s = 0; s < KSTEPS; ++s) {
        __syncthreads();                 // step s staged (also closes phase A at s=0)
        bf16x8 aN[2];
        if (s < KSTEPS - 1) {
            const int s1 = s + 1;
            #pragma unroll
            for (int i = 0; i < 2; ++i) {
                const unsigned short* g = Bp + (size_t)(s1 * 8 + wv * 2 + i) * 512 + lane * 8;
                __builtin_amdgcn_global_load_lds((const AS1 unsigned int*)g,
                                                 (AS3 unsigned int*)&bbuf[s1 & 1][(wv * 2 + i) * 512],
                                                 16, 0, 0);
            }
            if (s1 < 4) {
                #pragma unroll
                for (int mt = 0; mt < 2; ++mt)
                    aN[mt] = *(const bf16x8*)&xin[abase[mt] + (s1 & 3) * 32];
            } else {
                #pragma unroll
                for (int mt = 0; mt < 2; ++mt)
                    aN[mt] = *(const bf16x8*)&nh16[rloc[mt] * 136 + (s1 & 3) * 32 + quad * 8];
            }
        }
        bf16x8 bf[4];
        #pragma unroll
        for (int nt = 0; nt < 4; ++nt)
            bf[nt] = *(const bf16x8*)&bbuf[s & 1][(nw * 4 + nt) * 512 + lane * 8];
        #pragma unroll
        for (int mt = 0; mt < 2; ++mt)
            #pragma unroll
            for (int nt = 0; nt < 4; ++nt)
                acc[mt][nt] = __builtin_amdgcn_mfma_f32_16x16x32_bf16(aC[mt], bf[nt], acc[mt][nt], 0, 0, 0);
        #pragma unroll
        for (int mt = 0; mt < 2; ++mt) aC[mt] = aN[mt];
    }

    // bias + relu (C/D: row = quad*4 + r, col = lane&15; h = (nw*4+nt)*16 + col)
    float sbv[4], nbv[4], gv[4], bbv[4];
    #pragma unroll
    for (int nt = 0; nt < 4; ++nt) {
        const int hh = (nw * 4 + nt) * 16 + col;
        sbv[nt] = sb[hh]; nbv[nt] = nb[hh]; gv[nt] = lng[hh]; bbv[nt] = lnb[hh];
    }
    #pragma unroll
    for (int mt = 0; mt < 2; ++mt)
        #pragma unroll
        for (int nt = 0; nt < 4; ++nt)
            #pragma unroll
            for (int r = 0; r < 4; ++r)
                acc[mt][nt][r] = fmaxf(acc[mt][nt][r] + sbv[nt] + nbv[nt], 0.f);

    // LN partials
    #pragma unroll
    for (int mt = 0; mt < 2; ++mt)
        #pragma unroll
        for (int r = 0; r < 4; ++r) {
            float p = 0.f, q = 0.f;
            #pragma unroll
            for (int nt = 0; nt < 4; ++nt) {
                const float v = acc[mt][nt][r];
                p += v;
                q = fmaf(v, v, q);
            }
            p += __shfl_xor(p, 1);  q += __shfl_xor(q, 1);
            p += __shfl_xor(p, 2);  q += __shfl_xor(q, 2);
            p += __shfl_xor(p, 4);  q += __shfl_xor(q, 4);
            p += __shfl_xor(p, 8);  q += __shfl_xor(q, 8);
            if (col == 0) {
                const int rib = (mg * 2 + mt) * 16 + quad * 4 + r;
                lsum[nw][rib] = p;
                lsq[nw][rib] = q;
            }
        }
    __syncthreads();

    float psum[4] = {0.f, 0.f, 0.f, 0.f};
    float pmax[4] = {-INFINITY, -INFINITY, -INFINITY, -INFINITY};

    #pragma unroll
    for (int mt = 0; mt < 2; ++mt)
        #pragma unroll
        for (int r = 0; r < 4; ++r) {
            const int rib = (mg * 2 + mt) * 16 + quad * 4 + r;
            const int node = row0 + rib;
            const float mu = (lsum[0][rib] + lsum[1][rib]) * (1.f / H);
            const float var = (lsq[0][rib] + lsq[1][rib]) * (1.f / H) - mu * mu;
            const float isd = rsqrtf(var + EPS);
            const float m = nmask[node];
            #pragma unroll
            for (int nt = 0; nt < 4; ++nt) {
                const float y = (fmaf(acc[mt][nt][r] - mu, isd * gv[nt], bbv[nt])) * m;
                if (!last) {
                    xout[(size_t)node * H + (nw * 4 + nt) * 16 + col] = f2b(y);
                } else {
                    psum[nt] += y;
                    pmax[nt] = fmaxf(pmax[nt], (m > 0.f) ? y : -INFINITY);
                }
            }
        }

    if (!last) return;

    #pragma unroll
    for (int nt = 0; nt < 4; ++nt) {
        psum[nt] += __shfl_xor(psum[nt], 16);
        psum[nt] += __shfl_xor(psum[nt], 32);
        pmax[nt] = fmaxf(pmax[nt], __shfl_xor(pmax[nt], 16));
        pmax[nt] = fmaxf(pmax[nt], __shfl_xor(pmax[nt], 32));
    }
    if (quad == 0)
        #pragma unroll
        for (int nt = 0; nt < 4; ++nt) {
            psum_s[mg][(nw * 4 + nt) * 16 + col] = psum[nt];
            pmax_s[mg][(nw * 4 + nt) * 16 + col] = pmax[nt];
        }
    float nv = 0.f;
    if (wv == 0) {
        nv = nmask[row0 + lane];
        nv += __shfl_xor(nv, 1);  nv += __shfl_xor(nv, 2);
        nv += __shfl_xor(nv, 4);  nv += __shfl_xor(nv, 8);
        nv += __shfl_xor(nv, 16); nv += __shfl_xor(nv, 32);
    }
    __syncthreads();
    float* p = part + ((size_t)b * NCHUNK + chunk) * (2 * H + 1);
    if (tid < H) {
        p[tid] = psum_s[0][tid] + psum_s[1][tid];
        p[H + tid] = fmaxf(pmax_s[0][tid], pmax_s[1][tid]);
    }
    if (tid == 0) p[2 * H] = nv;
}

// ---------------- fused pool-reduce + MLP head (1024 threads, 4-way chunk split) ----------------
__global__ __launch_bounds__(1024) void k_tail2(const float* __restrict__ part,
                                                const float* __restrict__ W1, const float* __restrict__ b1,
                                                const float* __restrict__ W2, const float* __restrict__ b2,
                                                float* __restrict__ out) {
    const int b = blockIdx.x, tid = threadIdx.x;
    const int col = tid & 255;
    const int sub = tid >> 8;
    __shared__ float sred[4][2 * H];
    __shared__ float nvl[NCHUNK];
    __shared__ float g[2 * H];
    __shared__ float hid[H];
    {
        float acc = (col < H) ? 0.f : -INFINITY;
        #pragma unroll 8
        for (int c = sub * (NCHUNK / 4); c < (sub + 1) * (NCHUNK / 4); ++c) {
            const float v = part[((size_t)b * NCHUNK + c) * (2 * H + 1) + col];
            acc = (col < H) ? (acc + v) : fmaxf(acc, v);
        }
        sred[sub][col] = acc;
    }
    if (tid < NCHUNK)
        nvl[tid] = part[((size_t)b * NCHUNK + tid) * (2 * H + 1) + 2 * H];
    __syncthreads();
    for (int s = NCHUNK / 2; s > 0; s >>= 1) {
        if (tid < s) nvl[tid] += nvl[tid + s];
        __syncthreads();
    }
    const float nv = fmaxf(nvl[0], 1.f);
    if (tid < 2 * H) {
        if (tid < H)
            g[tid] = (sred[0][tid] + sred[1][tid] + sred[2][tid] + sred[3][tid]) / nv;
        else
            g[tid] = fmaxf(fmaxf(sred[0][tid], sred[1][tid]), fmaxf(sred[2][tid], sred[3][tid]));
    }
    __syncthreads();
    if (tid < H) {
        float a = b1[tid];
        #pragma unroll 8
        for (int k = 0; k < 2 * H; ++k) a = fmaf(g[k], W1[k * H + tid], a);
        hid[tid] = fmaxf(a, 0.f);
    }
    __syncthreads();
    if (tid < OUTD) {
        float a = b2[tid];
        #pragma unroll 8
        for (int k = 0; k < H; ++k) a = fmaf(hid[k], W2[k * OUTD + tid], a);
        out[(size_t)b * OUTD + tid] = a;
    }
}

extern "C" void kernel_launch(void* const* d_in, const int* in_sizes, int n_in,
                              void* d_out, int out_size, void* d_ws, size_t ws_size,
                              hipStream_t stream) {
    const float* feats = (const float*)d_in[0];
    const int*   ei    = (const int*)d_in[1];
    const float* nmask = (const float*)d_in[2];
    const float* emask = (const float*)d_in[3];
    const float* inW   = (const float*)d_in[4];
    const float* inb   = (const float*)d_in[5];
    const float* selfW = (const float*)d_in[6];
    const float* selfb = (const float*)d_in[7];
    const float* neighW= (const float*)d_in[8];
    const float* neighb= (const float*)d_in[9];
    const float* lng   = (const float*)d_in[10];
    const float* lnb   = (const float*)d_in[11];
    const float* W1    = (const float*)d_in[12];
    const float* b1    = (const float*)d_in[13];
    const float* W2    = (const float*)d_in[14];
    const float* b2    = (const float*)d_in[15];
    float* out = (float*)d_out;

    const size_t nxh = (size_t)NNODE * H;
    char* w = (char*)d_ws;
    unsigned short* xA  = (unsigned short*)w;  w += nxh * 2;
    unsigned short* xB  = (unsigned short*)w;  w += nxh * 2;
    unsigned short* Bp  = (unsigned short*)w;  w += (size_t)NLAYER * BPL * 2;
    unsigned short* Bpi = (unsigned short*)w;  w += (size_t)INSTEPS * 8 * 512 * 2;
    float* part = (float*)w;                   w += (size_t)B * NCHUNK * (2 * H + 1) * 4;
    int* ecnt   = (int*)w;                     w += (size_t)NNODE * 4;
    unsigned int* ell = (unsigned int*)w;      w += (size_t)NNODE * ELLW * 4;

    // node 1: prep (weights) + zero ecnt
    k_prep<<<PREPN + NNODE / 64, 64, 0, stream>>>(selfW, neighW, inW, Bp, Bpi, ecnt);
    // node 2: inproj || ELL fill
    k_front<<<1024 + B * E / 256, 256, 0, stream>>>(feats, Bpi, inb, xA, ei, emask, ecnt, ell);
    // nodes 3-5: fused gather+layer, ping-pong xA<->xB; last emits pool partials only
    k_fused2<<<NNODE / 64, 256, 0, stream>>>(xA, xB, ecnt, ell, Bp,
                                             selfb, neighb, lng, lnb, nmask, part, 0);
    k_fused2<<<NNODE / 64, 256, 0, stream>>>(xB, xA, ecnt, ell, Bp + (size_t)1 * BPL,
                                             selfb + H, neighb + H, lng + H, lnb + H,
                                             nmask, part, 0);
    k_fused2<<<NNODE / 64, 256, 0, stream>>>(xA, xB, ecnt, ell, Bp + (size_t)2 * BPL,
                                             selfb + 2 * H, neighb + 2 * H, lng + 2 * H, lnb + 2 * H,
                                             nmask, part, 1);
    // node 6: pool-reduce + MLP head
    k_tail2<<<B, 1024, 0, stream>>>(part, W1, b1, W2, b2, out);
}